// Round 1
// baseline (423.305 us; speedup 1.0000x reference)
//
#include <hip/hip_runtime.h>
#include <hip/hip_bf16.h>

using bf16 = __hip_bfloat16;
typedef __attribute__((ext_vector_type(8))) short bf16x8;
typedef __attribute__((ext_vector_type(4))) float f32x4;

#define BB   8
#define NN   12288
#define NTOK (BB*NN)      // 98304
#define NTK  3072
#define CC   256
#define CCO  512
#define HH   128
#define WWI  96
#define HWIN (HH*WWI)     // 12288
#define H2   64
#define W2   48
#define HW2  (H2*W2)      // 3072
#define RR   (BB*NTK)     // 24576

// ---- workspace layout (float-word offsets), end = 13233668 words = 52.93 MB
#define O_CONV  0LL          // conv bf16: 6291456 elems -> 3145728 words
#define O_XD    6291456LL    // xdf bf16 fragment layout: 6291456 elems -> 3145728 words
#define O_AUX   9437184LL    // 128 ints (scan block sums)
#define O_WT    12582912LL   // wTf bf16 fragment layout: 131072 elems -> 65536 words
#define O_ST1   12713984LL   // 512
#define O_ST2   12714496LL   // 1024 (contiguous with ST1)
#define O_AB1   12715520LL   // 512
#define O_B2    12716032LL   // 512
#define O_AB2   12716544LL   // 1024
#define O_FLAG  12717568LL   // 4
#define O_META  12717572LL   // 196608 (int2 per token {hw2, wv})
#define O_OFF   12914180LL   // 122880 ints: joint [cells(98304) | targets(24576)]
#define O_LIST  13037060LL   // 196608 ints: joint [listA | listB]
// end 13233668

__device__ __forceinline__ float cvt(float v){ return v; }
__device__ __forceinline__ float cvt(bf16 v){ return __bfloat162float(v); }
template<typename T>
__device__ __forceinline__ float ld(const void* p, long long i){
    return cvt(((const T*)p)[i]);
}
__device__ __forceinline__ float bfu(unsigned short u){
    return __uint_as_float((unsigned)u << 16);
}
__device__ __forceinline__ unsigned short ubf(float f){
    bf16 h = __float2bfloat16(f);
    return *(unsigned short*)&h;
}
// load 4 consecutive elements (first index i, i%4==0) as f32x4
template<typename T>
__device__ __forceinline__ f32x4 ld4(const void* p, long long i);
template<>
__device__ __forceinline__ f32x4 ld4<bf16>(const void* p, long long i){
    const ushort4 u = *(const ushort4*)((const unsigned short*)p + i);
    return (f32x4){bfu(u.x), bfu(u.y), bfu(u.z), bfu(u.w)};
}
template<>
__device__ __forceinline__ f32x4 ld4<float>(const void* p, long long i){
    const float4 v = *(const float4*)((const float*)p + i);
    return (f32x4){v.x, v.y, v.z, v.w};
}

// dtype detector: loc_orig ~ U(-1,1); f32 words all in [-1,1], bf16-reinterp huge.
__global__ void k_flag(const float* __restrict__ locf, float* __restrict__ flag){
    if (threadIdx.x == 0){
        int bad = 0;
        for (int i = 0; i < 64; ++i){
            const float v = locf[i];
            if (!(v >= -1.0f && v <= 1.0f)) bad = 1;
        }
        flag[0] = bad ? 1.0f : 0.0f;
    }
}

__device__ __forceinline__ int2 gidx2(float lx, float ly, int h, int w){
    lx = fminf(fmaxf(lx, -1.f), 1.f);
    ly = fminf(fmaxf(ly, -1.f), 1.f);
    int xi = (int)rintf(0.5f*(lx+1.f)*(float)w - 0.5f);
    int yi = (int)rintf(0.5f*(ly+1.f)*(float)h - 0.5f);
    xi = min(max(xi,0), w-1); yi = min(max(yi,0), h-1);
    return make_int2(xi, yi);
}

// K1: meta {hw2, wv} + joint histogram (cells then targets).
template<typename T>
__device__ void meta_body(const void* loc, const int* __restrict__ iat, const void* wt,
                          int2* __restrict__ meta, int* __restrict__ off){
    const int tok = blockIdx.x*256 + threadIdx.x;
    const int b = tok / NN;
    const float lx = ld<T>(loc, 2LL*tok);
    const float ly = ld<T>(loc, 2LL*tok + 1);
    const int2 g1 = gidx2(lx, ly, HH, WWI);
    const int2 g2 = gidx2(lx, ly, H2, W2);
    const float wv = ld<T>(wt, tok);
    int2 m; m.x = g2.x + g2.y*W2; m.y = __float_as_int(wv);
    meta[tok] = m;
    atomicAdd(&off[b*HWIN + g1.x + g1.y*WWI], 1);
    atomicAdd(&off[NTOK + b*NTK + iat[tok]], 1);
}
__global__ __launch_bounds__(256) void k_meta(
        const void* loc, const int* __restrict__ iat, const void* wt,
        const float* __restrict__ flag, int2* __restrict__ meta,
        int* __restrict__ off){
    if (flag[0] != 0.0f) meta_body<bf16>(loc, iat, wt, meta, off);
    else                 meta_body<float>(loc, iat, wt, meta, off);
}

// Scan over joint off[122880]: S1 per-block excl scan + totals, S2 scan totals, S3 add.
#define SCN  (NTOK + RR)     // 122880
#define SCB  120             // 120 blocks x 1024
__global__ __launch_bounds__(1024) void k_scan1(int* __restrict__ off, int* __restrict__ aux){
    __shared__ int sm[1024];
    const int tid = threadIdx.x;
    const int gid = blockIdx.x*1024 + tid;
    const int v = off[gid];
    sm[tid] = v;
    __syncthreads();
    for (int d = 1; d < 1024; d <<= 1){
        const int t = (tid >= d) ? sm[tid-d] : 0;
        __syncthreads();
        sm[tid] += t;
        __syncthreads();
    }
    off[gid] = sm[tid] - v;                    // exclusive within block
    if (tid == 1023) aux[blockIdx.x] = sm[1023];
}
__global__ __launch_bounds__(128) void k_scan2(int* __restrict__ aux){
    __shared__ int sm[128];
    const int tid = threadIdx.x;
    const int v = (tid < SCB) ? aux[tid] : 0;
    sm[tid] = v;
    __syncthreads();
    for (int d = 1; d < 128; d <<= 1){
        const int t = (tid >= d) ? sm[tid-d] : 0;
        __syncthreads();
        sm[tid] += t;
        __syncthreads();
    }
    if (tid < SCB) aux[tid] = sm[tid] - v;     // exclusive
}
__global__ __launch_bounds__(1024) void k_scan3(int* __restrict__ off, const int* __restrict__ aux){
    off[blockIdx.x*1024 + threadIdx.x] += aux[blockIdx.x];
}

// K3: fill joint CSR list. After this off holds inclusive ends.
template<typename T>
__device__ void fill_body(const void* loc, const int* __restrict__ ia,
                          const int* __restrict__ iat,
                          int* __restrict__ off, int* __restrict__ list){
    const int tok = blockIdx.x*256 + threadIdx.x;
    const int b = tok / NN;
    const float lx = ld<T>(loc, 2LL*tok);
    const float ly = ld<T>(loc, 2LL*tok + 1);
    const int2 g1 = gidx2(lx, ly, HH, WWI);
    const int pa = atomicAdd(&off[b*HWIN + g1.x + g1.y*WWI], 1);
    list[pa] = b*NN + ia[tok];
    const int pb = atomicAdd(&off[NTOK + b*NTK + iat[tok]], 1);
    list[pb] = tok;
}
__global__ __launch_bounds__(256) void k_fill(
        const void* loc, const int* __restrict__ ia, const int* __restrict__ iat,
        const float* __restrict__ flag,
        int* __restrict__ off, int* __restrict__ list){
    if (flag[0] != 0.0f) fill_body<bf16>(loc, ia, iat, off, list);
    else                 fill_body<float>(loc, ia, iat, off, list);
}

// K4: gather-conv, wave-per-output-cell, 4 ch/lane. Block = 4 waves = 4 cells.
template<typename T>
__device__ void conv_body(const void* x, const void* dww,
                          const int* __restrict__ off, const int* __restrict__ list,
                          bf16* __restrict__ conv){
    const int wave = threadIdx.x >> 6;
    const int lane = threadIdx.x & 63;
    const int ch0 = lane*4;
    const int cell = blockIdx.x*4 + wave;          // 0..24575
    const int b = cell / HW2;
    const int p = cell % HW2;
    const int oh = p / W2, ow = p % W2;
    float acc0 = 0.f, acc1 = 0.f, acc2 = 0.f, acc3 = 0.f;
    #pragma unroll
    for (int kh = 0; kh < 3; ++kh){
        const int ih = 2*oh - 1 + kh;
        if (ih < 0 || ih >= HH) continue;
        #pragma unroll
        for (int kw = 0; kw < 3; ++kw){
            const int iw = 2*ow - 1 + kw;
            if (iw < 0 || iw >= WWI) continue;
            const int g = b*HWIN + ih*WWI + iw;
            const int e = off[g];
            const int s = (g > 0) ? off[g-1] : 0;
            const int ln = e - s;
            if (ln == 0) continue;
            float s0=0.f, s1=0.f, s2=0.f, s3=0.f;
            for (int i = s; i < e; ++i){
                const int row = list[i];                       // broadcast
                const f32x4 xv = ld4<T>(x, (long long)row*CC + ch0);
                s0 += xv[0]; s1 += xv[1]; s2 += xv[2]; s3 += xv[3];
            }
            const float rl = 1.0f/((float)ln + 1e-6f);
            const int k = kh*3 + kw;
            acc0 += ld<T>(dww, (ch0  )*9 + k) * s0 * rl;
            acc1 += ld<T>(dww, (ch0+1)*9 + k) * s1 * rl;
            acc2 += ld<T>(dww, (ch0+2)*9 + k) * s2 * rl;
            acc3 += ld<T>(dww, (ch0+3)*9 + k) * s3 * rl;
        }
    }
    ushort4 o;
    o.x = ubf(acc0); o.y = ubf(acc1); o.z = ubf(acc2); o.w = ubf(acc3);
    *(ushort4*)((unsigned short*)conv + (long long)cell*CC + ch0) = o;
}
__global__ __launch_bounds__(256) void k_conv(
        const void* x, const void* dww, const float* __restrict__ flag,
        const int* __restrict__ off, const int* __restrict__ list,
        bf16* __restrict__ conv){
    if (flag[0] != 0.0f) conv_body<bf16>(x, dww, off, list, conv);
    else                 conv_body<float>(x, dww, off, list, conv);
}

// K5: per-target gather, wave-per-target (4 targets/wave serial), 4 ch/lane.
//     xd -> MFMA-A fragment layout bf16 + BN1 stats (LDS reduce, 1 atomic/ch/block).
#define TGW 4
template<typename T>
__device__ void num_body(const void* x, const bf16* __restrict__ conv,
                         const void* skw, const int* __restrict__ ia,
                         const int2* __restrict__ meta,
                         const int* __restrict__ off, const int* __restrict__ list,
                         bf16* __restrict__ xdf, float* __restrict__ st1){
    __shared__ float ss[CC], sq[CC];
    const int tid = threadIdx.x;
    ss[tid] = 0.f; sq[tid] = 0.f;
    __syncthreads();
    const int wave = tid >> 6;
    const int lane = tid & 63;
    const int ch0 = lane*4;
    const f32x4 sk = ld4<T>(skw, ch0);
    float sa0=0.f,sa1=0.f,sa2=0.f,sa3=0.f, qa0=0.f,qa1=0.f,qa2=0.f,qa3=0.f;
    const int W = blockIdx.x*4 + wave;             // global wave id, 0..6143
    for (int t = 0; t < TGW; ++t){
        const int gt = W*TGW + t;                  // target 0..24575
        const int b = gt / NTK;
        const int gj = NTOK + gt;
        const int e  = off[gj];
        const int s  = off[gj-1];
        float a0=0.f,a1=0.f,a2=0.f,a3=0.f, den=0.f;
        for (int i = s; i < e; ++i){
            const int tok = list[i];               // broadcast
            const int2 m = meta[tok];              // broadcast
            const float wv = __int_as_float(m.y);
            const int j = ia[tok];                 // broadcast
            const f32x4 xv = ld4<T>(x, ((long long)(b*NN + j))*CC + ch0);
            const f32x4 cv = ld4<bf16>(conv, ((long long)(b*HW2 + m.x))*CC + ch0);
            a0 += wv*(sk[0]*xv[0] + cv[0]);
            a1 += wv*(sk[1]*xv[1] + cv[1]);
            a2 += wv*(sk[2]*xv[2] + cv[2]);
            a3 += wv*(sk[3]*xv[3] + cv[3]);
            den += wv;
        }
        const float rl = 1.0f/(den + 1e-6f);
        const float v0 = a0*rl, v1 = a1*rl, v2 = a2*rl, v3 = a3*rl;
        ushort4 o; o.x = ubf(v0); o.y = ubf(v1); o.z = ubf(v2); o.w = ubf(v3);
        const long long bi = (long long)(gt >> 4)*4096 + (long long)(ch0 >> 3)*128
                           + (long long)(gt & 15)*8 + (ch0 & 7);
        *(ushort4*)((unsigned short*)xdf + bi) = o;
        sa0 += v0; sa1 += v1; sa2 += v2; sa3 += v3;
        qa0 += v0*v0; qa1 += v1*v1; qa2 += v2*v2; qa3 += v3*v3;
    }
    atomicAdd(&ss[ch0  ], sa0); atomicAdd(&sq[ch0  ], qa0);
    atomicAdd(&ss[ch0+1], sa1); atomicAdd(&sq[ch0+1], qa1);
    atomicAdd(&ss[ch0+2], sa2); atomicAdd(&sq[ch0+2], qa2);
    atomicAdd(&ss[ch0+3], sa3); atomicAdd(&sq[ch0+3], qa3);
    __syncthreads();
    atomicAdd(&st1[tid], ss[tid]);
    atomicAdd(&st1[CC + tid], sq[tid]);
}
__global__ __launch_bounds__(256) void k_num(
        const void* x, const bf16* __restrict__ conv, const void* skw,
        const int* __restrict__ ia, const int2* __restrict__ meta,
        const int* __restrict__ off, const int* __restrict__ list,
        const float* __restrict__ flag,
        bf16* __restrict__ xdf, float* __restrict__ st1){
    if (flag[0] != 0.0f) num_body<bf16>(x, conv, skw, ia, meta, off, list, xdf, st1);
    else                 num_body<float>(x, conv, skw, ia, meta, off, list, xdf, st1);
}

// K6: finalize BN1 (a1, bshift) and bias2[o] = sum_c bshift[c]*w[o,c].
template<typename T>
__device__ void bn1_body(const float* __restrict__ st1, const void* g1, const void* b1,
                         const void* cw, float* __restrict__ ab1, float* __restrict__ bias2){
    __shared__ float sb[CC];
    const int tid = threadIdx.x;
    if (tid < CC){
        const float mean = st1[tid]/(float)RR;
        const float var  = st1[CC + tid]/(float)RR - mean*mean;
        const float a  = ld<T>(g1, tid) * rsqrtf(var + 1e-5f);
        const float bb = ld<T>(b1, tid) - mean*a;
        ab1[tid] = a; ab1[CC + tid] = bb;
        sb[tid] = bb;
    }
    __syncthreads();
    float acc = 0.f;
    for (int c = 0; c < CC; ++c) acc += sb[c]*ld<T>(cw, (long long)tid*CC + c);
    bias2[tid] = acc;
}
__global__ __launch_bounds__(512) void k_bn1(
        const float* __restrict__ st1, const void* g1, const void* b1, const void* cw,
        const float* __restrict__ flag, float* __restrict__ ab1, float* __restrict__ bias2){
    if (flag[0] != 0.0f) bn1_body<bf16>(st1, g1, b1, cw, ab1, bias2);
    else                 bn1_body<float>(st1, g1, b1, cw, ab1, bias2);
}

// K6b: wTf in MFMA-B fragment layout (bf16)
template<typename T>
__device__ void wt_body(const void* cw, const float* __restrict__ ab1, bf16* __restrict__ wTf){
    const int c = blockIdx.x, o = threadIdx.x;
    const float v = ld<T>(cw, (long long)o*CC + c) * ab1[c];
    wTf[(((long long)(o >> 4)*32 + (c >> 3))*16 + (o & 15))*8 + (c & 7)] = __float2bfloat16(v);
}
__global__ __launch_bounds__(512) void k_wt(
        const void* cw, const float* __restrict__ ab1,
        const float* __restrict__ flag, bf16* __restrict__ wTf){
    if (flag[0] != 0.0f) wt_body<bf16>(cw, ab1, wTf);
    else                 wt_body<float>(cw, ab1, wTf);
}

// K7: MFMA GEMM. Block = 4 waves; wave = 16 rows x 128 cols.
//     2-D grid (384, 4): mb = blockIdx.x (384 NOT pow2 — do not mask!), nb = blockIdx.y.
__global__ __launch_bounds__(256) void k_gemm(
        const bf16* __restrict__ xdf, const bf16* __restrict__ wTf,
        const float* __restrict__ bias2, const float* __restrict__ flag,
        void* __restrict__ y, float* __restrict__ st2){
    __shared__ float ss[128], sq[128];
    const int tid = threadIdx.x;
    if (tid < 128){ ss[tid] = 0.f; sq[tid] = 0.f; }
    __syncthreads();
    const int wave = tid >> 6;
    const int lane = tid & 63;
    const int l16 = lane & 15;
    const int lq  = lane >> 4;
    const int mb = blockIdx.x;              // 0..383
    const int nb = blockIdx.y;              // 0..3
    const int mt = mb*4 + wave;             // m-tile (16 rows)
    const int n0t = nb*8;                   // first n-tile
    const short* ap = (const short*)xdf + ((long long)mt*32 + lq)*128 + (long long)l16*8;
    const short* bp = (const short*)wTf + ((long long)n0t*32 + lq)*128 + (long long)l16*8;
    f32x4 acc[8];
    #pragma unroll
    for (int nt = 0; nt < 8; ++nt) acc[nt] = (f32x4){0.f,0.f,0.f,0.f};
    #pragma unroll
    for (int kg0 = 0; kg0 < 8; ++kg0){
        const bf16x8 af = *((const bf16x8*)(ap + kg0*512));
        #pragma unroll
        for (int nt = 0; nt < 8; ++nt){
            const bf16x8 bfr = *((const bf16x8*)(bp + (long long)nt*4096 + kg0*512));
            acc[nt] = __builtin_amdgcn_mfma_f32_16x16x32_bf16(af, bfr, acc[nt], 0, 0, 0);
        }
    }
    const int row0 = mt*16 + lq*4;
    const bool isbf = (flag[0] != 0.0f);
    #pragma unroll
    for (int nt = 0; nt < 8; ++nt){
        const int col = nb*128 + nt*16 + l16;
        const float bz = bias2[col];
        float s = 0.f, q = 0.f;
        float v[4];
        #pragma unroll
        for (int r = 0; r < 4; ++r){
            v[r] = acc[nt][r] + bz;
            s += v[r]; q += v[r]*v[r];
        }
        if (isbf){
            bf16* yo = (bf16*)y;
            #pragma unroll
            for (int r = 0; r < 4; ++r)
                yo[(long long)(row0 + r)*CCO + col] = __float2bfloat16(v[r]);
        } else {
            float* yo = (float*)y;
            #pragma unroll
            for (int r = 0; r < 4; ++r)
                yo[(long long)(row0 + r)*CCO + col] = v[r];
        }
        s += __shfl_xor(s, 16); s += __shfl_xor(s, 32);
        q += __shfl_xor(q, 16); q += __shfl_xor(q, 32);
        if (lq == 0){
            atomicAdd(&ss[nt*16 + l16], s);
            atomicAdd(&sq[nt*16 + l16], q);
        }
    }
    __syncthreads();
    if (tid < 128){
        atomicAdd(&st2[nb*128 + tid], ss[tid]);
        atomicAdd(&st2[CCO + nb*128 + tid], sq[tid]);
    }
}

// K8: finalize BN2 scale/shift.
template<typename T>
__device__ void bn2_body(const float* __restrict__ st2, const void* g2, const void* b2,
                         float* __restrict__ ab2){
    const int tid = threadIdx.x;
    const float mean = st2[tid]/(float)RR;
    const float var  = st2[CCO + tid]/(float)RR - mean*mean;
    const float a = ld<T>(g2, tid) * rsqrtf(var + 1e-5f);
    ab2[tid] = a;
    ab2[CCO + tid] = ld<T>(b2, tid) - mean*a;
}
__global__ __launch_bounds__(512) void k_bn2(
        const float* __restrict__ st2, const void* g2, const void* b2,
        const float* __restrict__ flag, float* __restrict__ ab2){
    if (flag[0] != 0.0f) bn2_body<bf16>(st2, g2, b2, ab2);
    else                 bn2_body<float>(st2, g2, b2, ab2);
}

// K9: in-place on d_out: out = relu(y*a2 + b2), 4 elems/thread.
__global__ __launch_bounds__(256) void k_out(
        void* __restrict__ y, const float* __restrict__ ab2,
        const float* __restrict__ flag){
    const long long i0 = ((long long)blockIdx.x*256 + threadIdx.x)*4;
    const int o0 = (int)(i0 & (CCO-1));
    if (flag[0] != 0.0f){
        unsigned short* p = (unsigned short*)y;
        ushort4 u = *(ushort4*)(p + i0);
        float v0 = bfu(u.x)*ab2[o0  ] + ab2[CCO + o0  ];
        float v1 = bfu(u.y)*ab2[o0+1] + ab2[CCO + o0+1];
        float v2 = bfu(u.z)*ab2[o0+2] + ab2[CCO + o0+2];
        float v3 = bfu(u.w)*ab2[o0+3] + ab2[CCO + o0+3];
        u.x = ubf(fmaxf(v0,0.f)); u.y = ubf(fmaxf(v1,0.f));
        u.z = ubf(fmaxf(v2,0.f)); u.w = ubf(fmaxf(v3,0.f));
        *(ushort4*)(p + i0) = u;
    } else {
        float* p = (float*)y;
        float4 v = *(float4*)(p + i0);
        v.x = fmaxf(v.x*ab2[o0  ] + ab2[CCO + o0  ], 0.f);
        v.y = fmaxf(v.y*ab2[o0+1] + ab2[CCO + o0+1], 0.f);
        v.z = fmaxf(v.z*ab2[o0+2] + ab2[CCO + o0+2], 0.f);
        v.w = fmaxf(v.w*ab2[o0+3] + ab2[CCO + o0+3], 0.f);
        *(float4*)(p + i0) = v;
    }
}

extern "C" void kernel_launch(void* const* d_in, const int* in_sizes, int n_in,
                              void* d_out, int out_size, void* d_ws, size_t ws_size,
                              hipStream_t stream){
    (void)in_sizes; (void)n_in; (void)out_size; (void)ws_size;
    const void* x   = d_in[0];
    const void* loc = d_in[1];
    const int*  ia  = (const int*)d_in[2];
    const int*  iat = (const int*)d_in[5];
    const void* wt  = d_in[6];
    const void* dww = d_in[9];
    const void* skw = d_in[10];
    const void* g1  = d_in[11];
    const void* b1  = d_in[12];
    const void* cw  = d_in[13];
    const void* g2  = d_in[14];
    const void* b2  = d_in[15];
    float* ws = (float*)d_ws;
    float* flag = ws + O_FLAG;
    int*  off  = (int*)(ws + O_OFF);
    int*  list = (int*)(ws + O_LIST);
    int*  aux  = (int*)(ws + O_AUX);
    int2* meta = (int2*)(ws + O_META);
    bf16* conv = (bf16*)(ws + O_CONV);
    bf16* xdf  = (bf16*)(ws + O_XD);
    bf16* wTf  = (bf16*)(ws + O_WT);

    hipMemsetAsync(ws + O_ST1, 0, (size_t)1536*4, stream);
    hipMemsetAsync(off, 0, (size_t)SCN*4, stream);

    k_flag<<<dim3(1), dim3(64), 0, stream>>>((const float*)loc, flag);

    k_meta<<<dim3(NTOK/256), dim3(256), 0, stream>>>(loc, iat, wt, flag, meta, off);

    k_scan1<<<dim3(SCB), dim3(1024), 0, stream>>>(off, aux);
    k_scan2<<<dim3(1), dim3(128), 0, stream>>>(aux);
    k_scan3<<<dim3(SCB), dim3(1024), 0, stream>>>(off, aux);

    k_fill<<<dim3(NTOK/256), dim3(256), 0, stream>>>(loc, ia, iat, flag, off, list);

    k_conv<<<dim3(BB*HW2/4), dim3(256), 0, stream>>>(x, dww, flag, off, list, conv);

    k_num<<<dim3(RR/(4*TGW)), dim3(256), 0, stream>>>(
        x, conv, skw, ia, meta, off, list, flag, xdf, ws + O_ST1);

    k_bn1<<<dim3(1), dim3(512), 0, stream>>>(
        ws + O_ST1, g1, b1, cw, flag, ws + O_AB1, ws + O_B2);

    k_wt<<<dim3(CC), dim3(512), 0, stream>>>(cw, ws + O_AB1, flag, wTf);

    k_gemm<<<dim3(384, 4), dim3(256), 0, stream>>>(
        xdf, wTf, ws + O_B2, flag, d_out, ws + O_ST2);

    k_bn2<<<dim3(1), dim3(512), 0, stream>>>(ws + O_ST2, g2, b2, flag, ws + O_AB2);

    k_out<<<dim3((RR*CCO)/1024, 1), dim3(256), 0, stream>>>(d_out, ws + O_AB2, flag);
}

// Round 2
// 408.986 us; speedup vs baseline: 1.0350x; 1.0350x over previous
//
#include <hip/hip_runtime.h>
#include <hip/hip_bf16.h>

using bf16 = __hip_bfloat16;
typedef __attribute__((ext_vector_type(8))) short bf16x8;
typedef __attribute__((ext_vector_type(4))) float f32x4;

#define BB   8
#define NN   12288
#define NTOK (BB*NN)      // 98304
#define NTK  3072
#define CC   256
#define CCO  512
#define HH   128
#define WWI  96
#define HWIN (HH*WWI)     // 12288
#define H2   64
#define W2   48
#define HW2  (H2*W2)      // 3072
#define RR   (BB*NTK)     // 24576

// ---- workspace layout (float-word offsets), end = 13233668 words = 52.93 MB
#define O_CONV  0LL          // conv bf16: 6291456 elems -> 3145728 words
#define O_XD    6291456LL    // xdf bf16 fragment layout: 6291456 elems -> 3145728 words
#define O_AUX   9437184LL    // 128 ints (scan block sums)
#define O_WT    12582912LL   // wTf bf16 fragment layout: 131072 elems -> 65536 words
#define O_ST1   12713984LL   // 512
#define O_ST2   12714496LL   // 1024 (contiguous with ST1)
#define O_AB1   12715520LL   // 512
#define O_B2    12716032LL   // 512
#define O_AB2   12716544LL   // 1024
#define O_FLAG  12717568LL   // 4
#define O_META  12717572LL   // 196608 (int2 per token {hw2, wv})
#define O_OFF   12914180LL   // 122880 ints: joint [cells(98304) | targets(24576)]
#define O_LIST  13037060LL   // 196608 ints: joint [listA | listB]
// end 13233668

__device__ __forceinline__ float cvt(float v){ return v; }
__device__ __forceinline__ float cvt(bf16 v){ return __bfloat162float(v); }
template<typename T>
__device__ __forceinline__ float ld(const void* p, long long i){
    return cvt(((const T*)p)[i]);
}
__device__ __forceinline__ float bfu(unsigned short u){
    return __uint_as_float((unsigned)u << 16);
}
__device__ __forceinline__ unsigned short ubf(float f){
    bf16 h = __float2bfloat16(f);
    return *(unsigned short*)&h;
}
// load 4 consecutive elements (first index i, i%4==0) as f32x4
template<typename T>
__device__ __forceinline__ f32x4 ld4(const void* p, long long i);
template<>
__device__ __forceinline__ f32x4 ld4<bf16>(const void* p, long long i){
    const ushort4 u = *(const ushort4*)((const unsigned short*)p + i);
    return (f32x4){bfu(u.x), bfu(u.y), bfu(u.z), bfu(u.w)};
}
template<>
__device__ __forceinline__ f32x4 ld4<float>(const void* p, long long i){
    const float4 v = *(const float4*)((const float*)p + i);
    return (f32x4){v.x, v.y, v.z, v.w};
}

// dtype detector: loc_orig ~ U(-1,1); f32 words all in [-1,1], bf16-reinterp huge.
__global__ void k_flag(const float* __restrict__ locf, float* __restrict__ flag){
    if (threadIdx.x == 0){
        int bad = 0;
        for (int i = 0; i < 64; ++i){
            const float v = locf[i];
            if (!(v >= -1.0f && v <= 1.0f)) bad = 1;
        }
        flag[0] = bad ? 1.0f : 0.0f;
    }
}

__device__ __forceinline__ int2 gidx2(float lx, float ly, int h, int w){
    lx = fminf(fmaxf(lx, -1.f), 1.f);
    ly = fminf(fmaxf(ly, -1.f), 1.f);
    int xi = (int)rintf(0.5f*(lx+1.f)*(float)w - 0.5f);
    int yi = (int)rintf(0.5f*(ly+1.f)*(float)h - 0.5f);
    xi = min(max(xi,0), w-1); yi = min(max(yi,0), h-1);
    return make_int2(xi, yi);
}

// K1: meta {hw2, wv} + joint histogram (cells then targets).
template<typename T>
__device__ void meta_body(const void* loc, const int* __restrict__ iat, const void* wt,
                          int2* __restrict__ meta, int* __restrict__ off){
    const int tok = blockIdx.x*256 + threadIdx.x;
    const int b = tok / NN;
    const float lx = ld<T>(loc, 2LL*tok);
    const float ly = ld<T>(loc, 2LL*tok + 1);
    const int2 g1 = gidx2(lx, ly, HH, WWI);
    const int2 g2 = gidx2(lx, ly, H2, W2);
    const float wv = ld<T>(wt, tok);
    int2 m; m.x = g2.x + g2.y*W2; m.y = __float_as_int(wv);
    meta[tok] = m;
    atomicAdd(&off[b*HWIN + g1.x + g1.y*WWI], 1);
    atomicAdd(&off[NTOK + b*NTK + iat[tok]], 1);
}
__global__ __launch_bounds__(256) void k_meta(
        const void* loc, const int* __restrict__ iat, const void* wt,
        const float* __restrict__ flag, int2* __restrict__ meta,
        int* __restrict__ off){
    if (flag[0] != 0.0f) meta_body<bf16>(loc, iat, wt, meta, off);
    else                 meta_body<float>(loc, iat, wt, meta, off);
}

// Scan over joint off[122880]: S1 per-block excl scan + totals, S2 scan totals, S3 add.
#define SCN  (NTOK + RR)     // 122880
#define SCB  120             // 120 blocks x 1024
__global__ __launch_bounds__(1024) void k_scan1(int* __restrict__ off, int* __restrict__ aux){
    __shared__ int sm[1024];
    const int tid = threadIdx.x;
    const int gid = blockIdx.x*1024 + tid;
    const int v = off[gid];
    sm[tid] = v;
    __syncthreads();
    for (int d = 1; d < 1024; d <<= 1){
        const int t = (tid >= d) ? sm[tid-d] : 0;
        __syncthreads();
        sm[tid] += t;
        __syncthreads();
    }
    off[gid] = sm[tid] - v;                    // exclusive within block
    if (tid == 1023) aux[blockIdx.x] = sm[1023];
}
__global__ __launch_bounds__(128) void k_scan2(int* __restrict__ aux){
    __shared__ int sm[128];
    const int tid = threadIdx.x;
    const int v = (tid < SCB) ? aux[tid] : 0;
    sm[tid] = v;
    __syncthreads();
    for (int d = 1; d < 128; d <<= 1){
        const int t = (tid >= d) ? sm[tid-d] : 0;
        __syncthreads();
        sm[tid] += t;
        __syncthreads();
    }
    if (tid < SCB) aux[tid] = sm[tid] - v;     // exclusive
}
__global__ __launch_bounds__(1024) void k_scan3(int* __restrict__ off, const int* __restrict__ aux){
    off[blockIdx.x*1024 + threadIdx.x] += aux[blockIdx.x];
}

// K3: fill joint CSR list. After this off holds inclusive ends.
template<typename T>
__device__ void fill_body(const void* loc, const int* __restrict__ ia,
                          const int* __restrict__ iat,
                          int* __restrict__ off, int* __restrict__ list){
    const int tok = blockIdx.x*256 + threadIdx.x;
    const int b = tok / NN;
    const float lx = ld<T>(loc, 2LL*tok);
    const float ly = ld<T>(loc, 2LL*tok + 1);
    const int2 g1 = gidx2(lx, ly, HH, WWI);
    const int pa = atomicAdd(&off[b*HWIN + g1.x + g1.y*WWI], 1);
    list[pa] = b*NN + ia[tok];
    const int pb = atomicAdd(&off[NTOK + b*NTK + iat[tok]], 1);
    list[pb] = tok;
}
__global__ __launch_bounds__(256) void k_fill(
        const void* loc, const int* __restrict__ ia, const int* __restrict__ iat,
        const float* __restrict__ flag,
        int* __restrict__ off, int* __restrict__ list){
    if (flag[0] != 0.0f) fill_body<bf16>(loc, ia, iat, off, list);
    else                 fill_body<float>(loc, ia, iat, off, list);
}

// K4: gather-conv, wave-per-output-cell, 4 ch/lane. Block = 4 waves = 4 cells.
// Latency restructure (R1): the 3 kw positions of a kernel row are contiguous in
// the CSR list -> walk each row as ONE merged segment; recover the kw bucket by
// comparing the token's list index against the off[] boundaries. Lane-parallel
// list prefetch (one coalesced load/row), broadcast via __shfl, pipelined x loads.
template<typename T>
__device__ void conv_body(const void* x, const void* dww,
                          const int* __restrict__ off, const int* __restrict__ list,
                          bf16* __restrict__ conv){
    const int wave = threadIdx.x >> 6;
    const int lane = threadIdx.x & 63;
    const int ch0 = lane*4;
    const int cell = blockIdx.x*4 + wave;          // 0..24575
    const int b = cell / HW2;
    const int p = cell % HW2;
    const int oh = p / W2, ow = p % W2;

    // preload all 9 taps x 4 channels (independent loads, issued up front)
    f32x4 wreg[9];
    #pragma unroll
    for (int k = 0; k < 9; ++k)
        wreg[k] = (f32x4){ ld<T>(dww, (long long)(ch0  )*9 + k),
                           ld<T>(dww, (long long)(ch0+1)*9 + k),
                           ld<T>(dww, (long long)(ch0+2)*9 + k),
                           ld<T>(dww, (long long)(ch0+3)*9 + k) };

    const bool kw0v = (ow > 0);                    // iw=-1 only when ow==0
    f32x4 acc = (f32x4){0.f,0.f,0.f,0.f};
    #pragma unroll
    for (int kh = 0; kh < 3; ++kh){
        const int ih = 2*oh - 1 + kh;
        if (ih < 0 || ih >= HH) continue;          // only kh=0/oh=0 in practice
        const int gbase = b*HWIN + ih*WWI + 2*ow - 1;   // g of kw=0 cell
        const int e0 = (gbase >= 0) ? off[gbase] : 0;   // end of kw=0 bucket
        const int e1 = off[gbase+1];                    // end of kw=1 bucket
        const int e2 = off[gbase+2];                    // end of kw=2 bucket
        const int ms = kw0v ? off[gbase-1] : e0;        // merged start (gbase-1>=0 when kw0v)
        f32x4 b0 = (f32x4){0.f,0.f,0.f,0.f};
        f32x4 b1 = (f32x4){0.f,0.f,0.f,0.f};
        f32x4 b2 = (f32x4){0.f,0.f,0.f,0.f};
        int idx = ms;
        while (idx < e2){
            const int cnt = min(e2 - idx, 64);
            const int tokv = (lane < cnt) ? list[idx + lane] : 0;
            for (int j = 0; j < cnt; ++j){
                const int row = __shfl(tokv, j);               // uniform broadcast
                const f32x4 xv = ld4<T>(x, (long long)row*CC + ch0);
                const int gi = idx + j;                        // uniform -> uniform branch
                if (gi < e0)      b0 += xv;
                else if (gi < e1) b1 += xv;
                else              b2 += xv;
            }
            idx += cnt;
        }
        const float r0 = 1.0f/((float)(e0 - ms) + 1e-6f);
        const float r1 = 1.0f/((float)(e1 - e0) + 1e-6f);
        const float r2 = 1.0f/((float)(e2 - e1) + 1e-6f);
        const f32x4 w0 = wreg[kh*3+0], w1 = wreg[kh*3+1], w2 = wreg[kh*3+2];
        #pragma unroll
        for (int c = 0; c < 4; ++c)
            acc[c] += w0[c]*b0[c]*r0 + w1[c]*b1[c]*r1 + w2[c]*b2[c]*r2;
    }
    ushort4 o;
    o.x = ubf(acc[0]); o.y = ubf(acc[1]); o.z = ubf(acc[2]); o.w = ubf(acc[3]);
    *(ushort4*)((unsigned short*)conv + (long long)cell*CC + ch0) = o;
}
__global__ __launch_bounds__(256) void k_conv(
        const void* x, const void* dww, const float* __restrict__ flag,
        const int* __restrict__ off, const int* __restrict__ list,
        bf16* __restrict__ conv){
    if (flag[0] != 0.0f) conv_body<bf16>(x, dww, off, list, conv);
    else                 conv_body<float>(x, dww, off, list, conv);
}

// K5: per-target gather, wave-per-target (4 targets/wave serial), 4 ch/lane.
// Latency restructure (R1): lane-parallel prefetch of list/meta/ia (chained but
// parallel across lanes), broadcast via __shfl, pipelined x+conv row loads.
#define TGW 4
template<typename T>
__device__ void num_body(const void* x, const bf16* __restrict__ conv,
                         const void* skw, const int* __restrict__ ia,
                         const int2* __restrict__ meta,
                         const int* __restrict__ off, const int* __restrict__ list,
                         bf16* __restrict__ xdf, float* __restrict__ st1){
    __shared__ float ss[CC], sq[CC];
    const int tid = threadIdx.x;
    ss[tid] = 0.f; sq[tid] = 0.f;
    __syncthreads();
    const int wave = tid >> 6;
    const int lane = tid & 63;
    const int ch0 = lane*4;
    const f32x4 sk = ld4<T>(skw, ch0);
    float sa0=0.f,sa1=0.f,sa2=0.f,sa3=0.f, qa0=0.f,qa1=0.f,qa2=0.f,qa3=0.f;
    const int W = blockIdx.x*4 + wave;             // global wave id, 0..6143
    for (int t = 0; t < TGW; ++t){
        const int gt = W*TGW + t;                  // target 0..24575
        const int b = gt / NTK;
        const int gj = NTOK + gt;
        const int e  = off[gj];
        const int s  = off[gj-1];
        f32x4 a = (f32x4){0.f,0.f,0.f,0.f};
        float den = 0.f;
        int idx = s;
        while (idx < e){
            const int cnt = min(e - idx, 64);
            int tok = 0, ja = 0; int2 m = make_int2(0, 0);
            if (lane < cnt){
                tok = list[idx + lane];
                m = meta[tok];
                ja = ia[tok];
            }
            for (int j = 0; j < cnt; ++j){
                const float wv = __int_as_float(__shfl(m.y, j));
                const int rx = b*NN  + __shfl(ja, j);
                const int rc = b*HW2 + __shfl(m.x, j);
                const f32x4 xv = ld4<T>(x, (long long)rx*CC + ch0);
                const f32x4 cv = ld4<bf16>(conv, (long long)rc*CC + ch0);
                #pragma unroll
                for (int c = 0; c < 4; ++c)
                    a[c] += wv*(sk[c]*xv[c] + cv[c]);
                den += wv;
            }
            idx += cnt;
        }
        const float rl = 1.0f/(den + 1e-6f);
        const float v0 = a[0]*rl, v1 = a[1]*rl, v2 = a[2]*rl, v3 = a[3]*rl;
        ushort4 o; o.x = ubf(v0); o.y = ubf(v1); o.z = ubf(v2); o.w = ubf(v3);
        const long long bi = (long long)(gt >> 4)*4096 + (long long)(ch0 >> 3)*128
                           + (long long)(gt & 15)*8 + (ch0 & 7);
        *(ushort4*)((unsigned short*)xdf + bi) = o;
        sa0 += v0; sa1 += v1; sa2 += v2; sa3 += v3;
        qa0 += v0*v0; qa1 += v1*v1; qa2 += v2*v2; qa3 += v3*v3;
    }
    atomicAdd(&ss[ch0  ], sa0); atomicAdd(&sq[ch0  ], qa0);
    atomicAdd(&ss[ch0+1], sa1); atomicAdd(&sq[ch0+1], qa1);
    atomicAdd(&ss[ch0+2], sa2); atomicAdd(&sq[ch0+2], qa2);
    atomicAdd(&ss[ch0+3], sa3); atomicAdd(&sq[ch0+3], qa3);
    __syncthreads();
    atomicAdd(&st1[tid], ss[tid]);
    atomicAdd(&st1[CC + tid], sq[tid]);
}
__global__ __launch_bounds__(256) void k_num(
        const void* x, const bf16* __restrict__ conv, const void* skw,
        const int* __restrict__ ia, const int2* __restrict__ meta,
        const int* __restrict__ off, const int* __restrict__ list,
        const float* __restrict__ flag,
        bf16* __restrict__ xdf, float* __restrict__ st1){
    if (flag[0] != 0.0f) num_body<bf16>(x, conv, skw, ia, meta, off, list, xdf, st1);
    else                 num_body<float>(x, conv, skw, ia, meta, off, list, xdf, st1);
}

// K6: finalize BN1 (a1, bshift) and bias2[o] = sum_c bshift[c]*w[o,c].
template<typename T>
__device__ void bn1_body(const float* __restrict__ st1, const void* g1, const void* b1,
                         const void* cw, float* __restrict__ ab1, float* __restrict__ bias2){
    __shared__ float sb[CC];
    const int tid = threadIdx.x;
    if (tid < CC){
        const float mean = st1[tid]/(float)RR;
        const float var  = st1[CC + tid]/(float)RR - mean*mean;
        const float a  = ld<T>(g1, tid) * rsqrtf(var + 1e-5f);
        const float bb = ld<T>(b1, tid) - mean*a;
        ab1[tid] = a; ab1[CC + tid] = bb;
        sb[tid] = bb;
    }
    __syncthreads();
    float acc = 0.f;
    for (int c = 0; c < CC; ++c) acc += sb[c]*ld<T>(cw, (long long)tid*CC + c);
    bias2[tid] = acc;
}
__global__ __launch_bounds__(512) void k_bn1(
        const float* __restrict__ st1, const void* g1, const void* b1, const void* cw,
        const float* __restrict__ flag, float* __restrict__ ab1, float* __restrict__ bias2){
    if (flag[0] != 0.0f) bn1_body<bf16>(st1, g1, b1, cw, ab1, bias2);
    else                 bn1_body<float>(st1, g1, b1, cw, ab1, bias2);
}

// K6b: wTf in MFMA-B fragment layout (bf16)
template<typename T>
__device__ void wt_body(const void* cw, const float* __restrict__ ab1, bf16* __restrict__ wTf){
    const int c = blockIdx.x, o = threadIdx.x;
    const float v = ld<T>(cw, (long long)o*CC + c) * ab1[c];
    wTf[(((long long)(o >> 4)*32 + (c >> 3))*16 + (o & 15))*8 + (c & 7)] = __float2bfloat16(v);
}
__global__ __launch_bounds__(512) void k_wt(
        const void* cw, const float* __restrict__ ab1,
        const float* __restrict__ flag, bf16* __restrict__ wTf){
    if (flag[0] != 0.0f) wt_body<bf16>(cw, ab1, wTf);
    else                 wt_body<float>(cw, ab1, wTf);
}

// K7: MFMA GEMM. Block = 4 waves; wave = 16 rows x 128 cols.
//     2-D grid (384, 4): mb = blockIdx.x (384 NOT pow2 — do not mask!), nb = blockIdx.y.
__global__ __launch_bounds__(256) void k_gemm(
        const bf16* __restrict__ xdf, const bf16* __restrict__ wTf,
        const float* __restrict__ bias2, const float* __restrict__ flag,
        void* __restrict__ y, float* __restrict__ st2){
    __shared__ float ss[128], sq[128];
    const int tid = threadIdx.x;
    if (tid < 128){ ss[tid] = 0.f; sq[tid] = 0.f; }
    __syncthreads();
    const int wave = tid >> 6;
    const int lane = tid & 63;
    const int l16 = lane & 15;
    const int lq  = lane >> 4;
    const int mb = blockIdx.x;              // 0..383
    const int nb = blockIdx.y;              // 0..3
    const int mt = mb*4 + wave;             // m-tile (16 rows)
    const int n0t = nb*8;                   // first n-tile
    const short* ap = (const short*)xdf + ((long long)mt*32 + lq)*128 + (long long)l16*8;
    const short* bp = (const short*)wTf + ((long long)n0t*32 + lq)*128 + (long long)l16*8;
    f32x4 acc[8];
    #pragma unroll
    for (int nt = 0; nt < 8; ++nt) acc[nt] = (f32x4){0.f,0.f,0.f,0.f};
    #pragma unroll
    for (int kg0 = 0; kg0 < 8; ++kg0){
        const bf16x8 af = *((const bf16x8*)(ap + kg0*512));
        #pragma unroll
        for (int nt = 0; nt < 8; ++nt){
            const bf16x8 bfr = *((const bf16x8*)(bp + (long long)nt*4096 + kg0*512));
            acc[nt] = __builtin_amdgcn_mfma_f32_16x16x32_bf16(af, bfr, acc[nt], 0, 0, 0);
        }
    }
    const int row0 = mt*16 + lq*4;
    const bool isbf = (flag[0] != 0.0f);
    #pragma unroll
    for (int nt = 0; nt < 8; ++nt){
        const int col = nb*128 + nt*16 + l16;
        const float bz = bias2[col];
        float s = 0.f, q = 0.f;
        float v[4];
        #pragma unroll
        for (int r = 0; r < 4; ++r){
            v[r] = acc[nt][r] + bz;
            s += v[r]; q += v[r]*v[r];
        }
        if (isbf){
            bf16* yo = (bf16*)y;
            #pragma unroll
            for (int r = 0; r < 4; ++r)
                yo[(long long)(row0 + r)*CCO + col] = __float2bfloat16(v[r]);
        } else {
            float* yo = (float*)y;
            #pragma unroll
            for (int r = 0; r < 4; ++r)
                yo[(long long)(row0 + r)*CCO + col] = v[r];
        }
        s += __shfl_xor(s, 16); s += __shfl_xor(s, 32);
        q += __shfl_xor(q, 16); q += __shfl_xor(q, 32);
        if (lq == 0){
            atomicAdd(&ss[nt*16 + l16], s);
            atomicAdd(&sq[nt*16 + l16], q);
        }
    }
    __syncthreads();
    if (tid < 128){
        atomicAdd(&st2[nb*128 + tid], ss[tid]);
        atomicAdd(&st2[CCO + nb*128 + tid], sq[tid]);
    }
}

// K8: finalize BN2 scale/shift.
template<typename T>
__device__ void bn2_body(const float* __restrict__ st2, const void* g2, const void* b2,
                         float* __restrict__ ab2){
    const int tid = threadIdx.x;
    const float mean = st2[tid]/(float)RR;
    const float var  = st2[CCO + tid]/(float)RR - mean*mean;
    const float a = ld<T>(g2, tid) * rsqrtf(var + 1e-5f);
    ab2[tid] = a;
    ab2[CCO + tid] = ld<T>(b2, tid) - mean*a;
}
__global__ __launch_bounds__(512) void k_bn2(
        const float* __restrict__ st2, const void* g2, const void* b2,
        const float* __restrict__ flag, float* __restrict__ ab2){
    if (flag[0] != 0.0f) bn2_body<bf16>(st2, g2, b2, ab2);
    else                 bn2_body<float>(st2, g2, b2, ab2);
}

// K9: in-place on d_out: out = relu(y*a2 + b2), 4 elems/thread.
__global__ __launch_bounds__(256) void k_out(
        void* __restrict__ y, const float* __restrict__ ab2,
        const float* __restrict__ flag){
    const long long i0 = ((long long)blockIdx.x*256 + threadIdx.x)*4;
    const int o0 = (int)(i0 & (CCO-1));
    if (flag[0] != 0.0f){
        unsigned short* p = (unsigned short*)y;
        ushort4 u = *(ushort4*)(p + i0);
        float v0 = bfu(u.x)*ab2[o0  ] + ab2[CCO + o0  ];
        float v1 = bfu(u.y)*ab2[o0+1] + ab2[CCO + o0+1];
        float v2 = bfu(u.z)*ab2[o0+2] + ab2[CCO + o0+2];
        float v3 = bfu(u.w)*ab2[o0+3] + ab2[CCO + o0+3];
        u.x = ubf(fmaxf(v0,0.f)); u.y = ubf(fmaxf(v1,0.f));
        u.z = ubf(fmaxf(v2,0.f)); u.w = ubf(fmaxf(v3,0.f));
        *(ushort4*)(p + i0) = u;
    } else {
        float* p = (float*)y;
        float4 v = *(float4*)(p + i0);
        v.x = fmaxf(v.x*ab2[o0  ] + ab2[CCO + o0  ], 0.f);
        v.y = fmaxf(v.y*ab2[o0+1] + ab2[CCO + o0+1], 0.f);
        v.z = fmaxf(v.z*ab2[o0+2] + ab2[CCO + o0+2], 0.f);
        v.w = fmaxf(v.w*ab2[o0+3] + ab2[CCO + o0+3], 0.f);
        *(float4*)(p + i0) = v;
    }
}

extern "C" void kernel_launch(void* const* d_in, const int* in_sizes, int n_in,
                              void* d_out, int out_size, void* d_ws, size_t ws_size,
                              hipStream_t stream){
    (void)in_sizes; (void)n_in; (void)out_size; (void)ws_size;
    const void* x   = d_in[0];
    const void* loc = d_in[1];
    const int*  ia  = (const int*)d_in[2];
    const int*  iat = (const int*)d_in[5];
    const void* wt  = d_in[6];
    const void* dww = d_in[9];
    const void* skw = d_in[10];
    const void* g1  = d_in[11];
    const void* b1  = d_in[12];
    const void* cw  = d_in[13];
    const void* g2  = d_in[14];
    const void* b2  = d_in[15];
    float* ws = (float*)d_ws;
    float* flag = ws + O_FLAG;
    int*  off  = (int*)(ws + O_OFF);
    int*  list = (int*)(ws + O_LIST);
    int*  aux  = (int*)(ws + O_AUX);
    int2* meta = (int2*)(ws + O_META);
    bf16* conv = (bf16*)(ws + O_CONV);
    bf16* xdf  = (bf16*)(ws + O_XD);
    bf16* wTf  = (bf16*)(ws + O_WT);

    hipMemsetAsync(ws + O_ST1, 0, (size_t)1536*4, stream);
    hipMemsetAsync(off, 0, (size_t)SCN*4, stream);

    k_flag<<<dim3(1), dim3(64), 0, stream>>>((const float*)loc, flag);

    k_meta<<<dim3(NTOK/256), dim3(256), 0, stream>>>(loc, iat, wt, flag, meta, off);

    k_scan1<<<dim3(SCB), dim3(1024), 0, stream>>>(off, aux);
    k_scan2<<<dim3(1), dim3(128), 0, stream>>>(aux);
    k_scan3<<<dim3(SCB), dim3(1024), 0, stream>>>(off, aux);

    k_fill<<<dim3(NTOK/256), dim3(256), 0, stream>>>(loc, ia, iat, flag, off, list);

    k_conv<<<dim3(BB*HW2/4), dim3(256), 0, stream>>>(x, dww, flag, off, list, conv);

    k_num<<<dim3(RR/(4*TGW)), dim3(256), 0, stream>>>(
        x, conv, skw, ia, meta, off, list, flag, xdf, ws + O_ST1);

    k_bn1<<<dim3(1), dim3(512), 0, stream>>>(
        ws + O_ST1, g1, b1, cw, flag, ws + O_AB1, ws + O_B2);

    k_wt<<<dim3(CC), dim3(512), 0, stream>>>(cw, ws + O_AB1, flag, wTf);

    k_gemm<<<dim3(384, 4), dim3(256), 0, stream>>>(
        xdf, wTf, ws + O_B2, flag, d_out, ws + O_ST2);

    k_bn2<<<dim3(1), dim3(512), 0, stream>>>(ws + O_ST2, g2, b2, flag, ws + O_AB2);

    k_out<<<dim3((RR*CCO)/1024, 1), dim3(256), 0, stream>>>(d_out, ws + O_AB2, flag);
}

// Round 3
// 405.004 us; speedup vs baseline: 1.0452x; 1.0098x over previous
//
#include <hip/hip_runtime.h>
#include <hip/hip_bf16.h>

using bf16 = __hip_bfloat16;
typedef __attribute__((ext_vector_type(8))) short bf16x8;
typedef __attribute__((ext_vector_type(4))) float f32x4;

#define BB   8
#define NN   12288
#define NTOK (BB*NN)      // 98304
#define NTK  3072
#define CC   256
#define CCO  512
#define HH   128
#define WWI  96
#define HWIN (HH*WWI)     // 12288
#define H2   64
#define W2   48
#define HW2  (H2*W2)      // 3072
#define RR   (BB*NTK)     // 24576

// ---- workspace layout (float-word offsets), end = 13233668 words = 52.93 MB
#define O_CONV  0LL          // conv bf16: 6291456 elems -> 3145728 words
#define O_XD    6291456LL    // xdf bf16 fragment layout: 6291456 elems -> 3145728 words
#define O_AUX   9437184LL    // 128 ints (scan block sums)
#define O_WT    12582912LL   // wTf bf16 fragment layout: 131072 elems -> 65536 words
#define O_ST1   12713984LL   // 512
#define O_ST2   12714496LL   // 1024 (contiguous with ST1)
#define O_AB1   12715520LL   // 512
#define O_B2    12716032LL   // 512
#define O_AB2   12716544LL   // 1024
#define O_FLAG  12717568LL   // 4
#define O_META  12717572LL   // 196608 (int2 per token {hw2, wv})
#define O_OFF   12914180LL   // 122880 ints: joint [cells(98304) | targets(24576)]
#define O_LIST  13037060LL   // 196608 ints: joint [listA | listB]
// end 13233668

__device__ __forceinline__ float cvt(float v){ return v; }
__device__ __forceinline__ float cvt(bf16 v){ return __bfloat162float(v); }
template<typename T>
__device__ __forceinline__ float ld(const void* p, long long i){
    return cvt(((const T*)p)[i]);
}
__device__ __forceinline__ float bfu(unsigned short u){
    return __uint_as_float((unsigned)u << 16);
}
__device__ __forceinline__ unsigned short ubf(float f){
    bf16 h = __float2bfloat16(f);
    return *(unsigned short*)&h;
}
// load 4 consecutive elements (first index i, i%4==0) as f32x4
template<typename T>
__device__ __forceinline__ f32x4 ld4(const void* p, long long i);
template<>
__device__ __forceinline__ f32x4 ld4<bf16>(const void* p, long long i){
    const ushort4 u = *(const ushort4*)((const unsigned short*)p + i);
    return (f32x4){bfu(u.x), bfu(u.y), bfu(u.z), bfu(u.w)};
}
template<>
__device__ __forceinline__ f32x4 ld4<float>(const void* p, long long i){
    const float4 v = *(const float4*)((const float*)p + i);
    return (f32x4){v.x, v.y, v.z, v.w};
}

// dtype detector: loc_orig ~ U(-1,1); f32 words all in [-1,1], bf16-reinterp huge.
__global__ void k_flag(const float* __restrict__ locf, float* __restrict__ flag){
    if (threadIdx.x == 0){
        int bad = 0;
        for (int i = 0; i < 64; ++i){
            const float v = locf[i];
            if (!(v >= -1.0f && v <= 1.0f)) bad = 1;
        }
        flag[0] = bad ? 1.0f : 0.0f;
    }
}

__device__ __forceinline__ int2 gidx2(float lx, float ly, int h, int w){
    lx = fminf(fmaxf(lx, -1.f), 1.f);
    ly = fminf(fmaxf(ly, -1.f), 1.f);
    int xi = (int)rintf(0.5f*(lx+1.f)*(float)w - 0.5f);
    int yi = (int)rintf(0.5f*(ly+1.f)*(float)h - 0.5f);
    xi = min(max(xi,0), w-1); yi = min(max(yi,0), h-1);
    return make_int2(xi, yi);
}

// K1: meta {hw2, wv} + joint histogram (cells then targets).
template<typename T>
__device__ void meta_body(const void* loc, const int* __restrict__ iat, const void* wt,
                          int2* __restrict__ meta, int* __restrict__ off){
    const int tok = blockIdx.x*256 + threadIdx.x;
    const int b = tok / NN;
    const float lx = ld<T>(loc, 2LL*tok);
    const float ly = ld<T>(loc, 2LL*tok + 1);
    const int2 g1 = gidx2(lx, ly, HH, WWI);
    const int2 g2 = gidx2(lx, ly, H2, W2);
    const float wv = ld<T>(wt, tok);
    int2 m; m.x = g2.x + g2.y*W2; m.y = __float_as_int(wv);
    meta[tok] = m;
    atomicAdd(&off[b*HWIN + g1.x + g1.y*WWI], 1);
    atomicAdd(&off[NTOK + b*NTK + iat[tok]], 1);
}
__global__ __launch_bounds__(256) void k_meta(
        const void* loc, const int* __restrict__ iat, const void* wt,
        const float* __restrict__ flag, int2* __restrict__ meta,
        int* __restrict__ off){
    if (flag[0] != 0.0f) meta_body<bf16>(loc, iat, wt, meta, off);
    else                 meta_body<float>(loc, iat, wt, meta, off);
}

// Scan over joint off[122880]: S1 per-block excl scan + totals, S2 scan totals, S3 add.
#define SCN  (NTOK + RR)     // 122880
#define SCB  120             // 120 blocks x 1024
__global__ __launch_bounds__(1024) void k_scan1(int* __restrict__ off, int* __restrict__ aux){
    __shared__ int sm[1024];
    const int tid = threadIdx.x;
    const int gid = blockIdx.x*1024 + tid;
    const int v = off[gid];
    sm[tid] = v;
    __syncthreads();
    for (int d = 1; d < 1024; d <<= 1){
        const int t = (tid >= d) ? sm[tid-d] : 0;
        __syncthreads();
        sm[tid] += t;
        __syncthreads();
    }
    off[gid] = sm[tid] - v;                    // exclusive within block
    if (tid == 1023) aux[blockIdx.x] = sm[1023];
}
__global__ __launch_bounds__(128) void k_scan2(int* __restrict__ aux){
    __shared__ int sm[128];
    const int tid = threadIdx.x;
    const int v = (tid < SCB) ? aux[tid] : 0;
    sm[tid] = v;
    __syncthreads();
    for (int d = 1; d < 128; d <<= 1){
        const int t = (tid >= d) ? sm[tid-d] : 0;
        __syncthreads();
        sm[tid] += t;
        __syncthreads();
    }
    if (tid < SCB) aux[tid] = sm[tid] - v;     // exclusive
}
__global__ __launch_bounds__(1024) void k_scan3(int* __restrict__ off, const int* __restrict__ aux){
    off[blockIdx.x*1024 + threadIdx.x] += aux[blockIdx.x];
}

// K3: fill joint CSR list. After this off holds inclusive ends.
template<typename T>
__device__ void fill_body(const void* loc, const int* __restrict__ ia,
                          const int* __restrict__ iat,
                          int* __restrict__ off, int* __restrict__ list){
    const int tok = blockIdx.x*256 + threadIdx.x;
    const int b = tok / NN;
    const float lx = ld<T>(loc, 2LL*tok);
    const float ly = ld<T>(loc, 2LL*tok + 1);
    const int2 g1 = gidx2(lx, ly, HH, WWI);
    const int pa = atomicAdd(&off[b*HWIN + g1.x + g1.y*WWI], 1);
    list[pa] = b*NN + ia[tok];
    const int pb = atomicAdd(&off[NTOK + b*NTK + iat[tok]], 1);
    list[pb] = tok;
}
__global__ __launch_bounds__(256) void k_fill(
        const void* loc, const int* __restrict__ ia, const int* __restrict__ iat,
        const float* __restrict__ flag,
        int* __restrict__ off, int* __restrict__ list){
    if (flag[0] != 0.0f) fill_body<bf16>(loc, ia, iat, off, list);
    else                 fill_body<float>(loc, ia, iat, off, list);
}

// K4: gather-conv, R3 restructure: wave-per-(cell,row). Block = 192 thr = 3 waves
// (wave index = kh). Per wave: one uniform off fetch, lane-parallel list batch,
// 4-unrolled x-row loads (8 loads in flight), bucket binning by list index.
// Rows combine via LDS; wave 0 stores bf16.
template<typename T>
__device__ void conv_body(const void* x, const void* dww,
                          const int* __restrict__ off, const int* __restrict__ list,
                          bf16* __restrict__ conv){
    __shared__ f32x4 red[3][64];
    const int tid = threadIdx.x;
    const int kh = tid >> 6;                       // 0..2 (wave = kernel row)
    const int lane = tid & 63;
    const int ch0 = lane*4;
    const int cell = blockIdx.x;                   // 0..24575
    const int b = cell / HW2;
    const int p = cell % HW2;
    const int oh = p / W2, ow = p % W2;
    const int ih = 2*oh - 1 + kh;                  // [-1, 127]; only -1 invalid
    f32x4 part = (f32x4){0.f,0.f,0.f,0.f};
    if (ih >= 0){
        const int gbase = b*HWIN + ih*WWI + 2*ow - 1;   // cell of kw=0
        const int e0 = (gbase >= 0) ? off[gbase] : 0;   // end kw=0 / start kw=1
        const int e1 = off[gbase+1];
        const int e2 = off[gbase+2];
        const int ms = (ow > 0) ? off[gbase-1] : e0;    // merged start
        // 3 taps x 4 channels for this row (independent, issued early)
        f32x4 w0, w1, w2;
        #pragma unroll
        for (int c = 0; c < 4; ++c){
            w0[c] = ld<T>(dww, (long long)(ch0+c)*9 + kh*3 + 0);
            w1[c] = ld<T>(dww, (long long)(ch0+c)*9 + kh*3 + 1);
            w2[c] = ld<T>(dww, (long long)(ch0+c)*9 + kh*3 + 2);
        }
        f32x4 b0 = (f32x4){0.f,0.f,0.f,0.f};
        f32x4 b1 = (f32x4){0.f,0.f,0.f,0.f};
        f32x4 b2 = (f32x4){0.f,0.f,0.f,0.f};
        int idx = ms;
        while (idx < e2){
            const int cnt = min(e2 - idx, 64);
            const int tokv = (lane < cnt) ? list[idx + lane] : 0;
            int j = 0;
            for (; j + 4 <= cnt; j += 4){
                int oxs[4];
                #pragma unroll
                for (int u = 0; u < 4; ++u)
                    oxs[u] = __shfl(tokv, j+u)*CC + ch0;
                f32x4 xv[4];
                #pragma unroll
                for (int u = 0; u < 4; ++u) xv[u] = ld4<T>(x, (long long)oxs[u]);
                #pragma unroll
                for (int u = 0; u < 4; ++u){
                    const int gi = idx + j + u;        // uniform
                    if (gi < e0)      b0 += xv[u];
                    else if (gi < e1) b1 += xv[u];
                    else              b2 += xv[u];
                }
            }
            for (; j < cnt; ++j){
                const f32x4 xv = ld4<T>(x, (long long)(__shfl(tokv, j)*CC + ch0));
                const int gi = idx + j;
                if (gi < e0)      b0 += xv;
                else if (gi < e1) b1 += xv;
                else              b2 += xv;
            }
            idx += cnt;
        }
        const float r0 = 1.0f/((float)(e0 - ms) + 1e-6f);
        const float r1 = 1.0f/((float)(e1 - e0) + 1e-6f);
        const float r2 = 1.0f/((float)(e2 - e1) + 1e-6f);
        #pragma unroll
        for (int c = 0; c < 4; ++c)
            part[c] = w0[c]*b0[c]*r0 + w1[c]*b1[c]*r1 + w2[c]*b2[c]*r2;
    }
    red[kh][lane] = part;
    __syncthreads();
    if (kh == 0){
        const f32x4 t0 = red[0][lane];
        const f32x4 t1 = red[1][lane];
        const f32x4 t2 = red[2][lane];
        ushort4 o;
        o.x = ubf(t0[0]+t1[0]+t2[0]);
        o.y = ubf(t0[1]+t1[1]+t2[1]);
        o.z = ubf(t0[2]+t1[2]+t2[2]);
        o.w = ubf(t0[3]+t1[3]+t2[3]);
        *(ushort4*)((unsigned short*)conv + (long long)cell*CC + ch0) = o;
    }
}
__global__ __launch_bounds__(192) void k_conv(
        const void* x, const void* dww, const float* __restrict__ flag,
        const int* __restrict__ off, const int* __restrict__ list,
        bf16* __restrict__ conv){
    if (flag[0] != 0.0f) conv_body<bf16>(x, dww, off, list, conv);
    else                 conv_body<float>(x, dww, off, list, conv);
}

// K5: R3 restructure: wave handles TGW=2 consecutive targets = ONE contiguous
// listB range. Single off fetch (lane<=TGW), single lane-parallel list/meta/ia
// batch, 4-unrolled leaf loads, static per-target accumulators via uniform
// boundary compare. xd -> MFMA-A fragment layout bf16 + BN1 stats.
#define TGW 2
template<typename T>
__device__ void num_body(const void* x, const bf16* __restrict__ conv,
                         const void* skw, const int* __restrict__ ia,
                         const int2* __restrict__ meta,
                         const int* __restrict__ off, const int* __restrict__ list,
                         bf16* __restrict__ xdf, float* __restrict__ st1){
    __shared__ float ss[CC], sq[CC];
    const int tid = threadIdx.x;
    ss[tid] = 0.f; sq[tid] = 0.f;
    __syncthreads();
    const int wave = tid >> 6;
    const int lane = tid & 63;
    const int ch0 = lane*4;
    const f32x4 sk = ld4<T>(skw, ch0);
    const int W = blockIdx.x*4 + wave;             // wave id 0..12287
    const int gt0 = W*TGW;                         // first target (same b for both)
    const int b = gt0 / NTK;
    int offv = 0;
    if (lane <= TGW) offv = off[NTOK + gt0 - 1 + lane];
    const int s0  = __shfl(offv, 0);
    const int eb0 = __shfl(offv, 1);               // end of target 0
    const int eb1 = __shfl(offv, 2);               // end of target 1
    f32x4 a0 = (f32x4){0.f,0.f,0.f,0.f};
    f32x4 a1 = (f32x4){0.f,0.f,0.f,0.f};
    float d0 = 0.f, d1 = 0.f;
    int idx = s0;
    while (idx < eb1){
        const int cnt = min(eb1 - idx, 64);
        int tok = 0, ja = 0; int2 m = make_int2(0, 0);
        if (lane < cnt){
            tok = list[idx + lane];
            m = meta[tok];
            ja = ia[tok];
        }
        int j = 0;
        for (; j + 4 <= cnt; j += 4){
            float wv[4]; int ox[4], oc[4];
            #pragma unroll
            for (int u = 0; u < 4; ++u){
                wv[u] = __int_as_float(__shfl(m.y, j+u));
                ox[u] = (b*NN  + __shfl(ja,  j+u))*CC + ch0;
                oc[u] = (b*HW2 + __shfl(m.x, j+u))*CC + ch0;
            }
            f32x4 xv[4], cv[4];
            #pragma unroll
            for (int u = 0; u < 4; ++u) xv[u] = ld4<T>(x, (long long)ox[u]);
            #pragma unroll
            for (int u = 0; u < 4; ++u) cv[u] = ld4<bf16>(conv, (long long)oc[u]);
            #pragma unroll
            for (int u = 0; u < 4; ++u){
                f32x4 cb;
                #pragma unroll
                for (int c = 0; c < 4; ++c) cb[c] = wv[u]*(sk[c]*xv[u][c] + cv[u][c]);
                if (idx + j + u < eb0){ a0 += cb; d0 += wv[u]; }
                else                  { a1 += cb; d1 += wv[u]; }
            }
        }
        for (; j < cnt; ++j){
            const float wv = __int_as_float(__shfl(m.y, j));
            const int ox = (b*NN  + __shfl(ja,  j))*CC + ch0;
            const int oc = (b*HW2 + __shfl(m.x, j))*CC + ch0;
            const f32x4 xv = ld4<T>(x, (long long)ox);
            const f32x4 cv = ld4<bf16>(conv, (long long)oc);
            f32x4 cb;
            #pragma unroll
            for (int c = 0; c < 4; ++c) cb[c] = wv*(sk[c]*xv[c] + cv[c]);
            if (idx + j < eb0){ a0 += cb; d0 += wv; }
            else              { a1 += cb; d1 += wv; }
        }
        idx += cnt;
    }
    float sa0=0.f,sa1=0.f,sa2=0.f,sa3=0.f, qa0=0.f,qa1=0.f,qa2=0.f,qa3=0.f;
    #pragma unroll
    for (int t = 0; t < TGW; ++t){
        const f32x4 a  = (t == 0) ? a0 : a1;
        const float dn = (t == 0) ? d0 : d1;
        const int gt = gt0 + t;
        const float rl = 1.0f/(dn + 1e-6f);
        const float v0 = a[0]*rl, v1 = a[1]*rl, v2 = a[2]*rl, v3 = a[3]*rl;
        ushort4 o; o.x = ubf(v0); o.y = ubf(v1); o.z = ubf(v2); o.w = ubf(v3);
        const long long bi = (long long)(gt >> 4)*4096 + (long long)(ch0 >> 3)*128
                           + (long long)(gt & 15)*8 + (ch0 & 7);
        *(ushort4*)((unsigned short*)xdf + bi) = o;
        sa0 += v0; sa1 += v1; sa2 += v2; sa3 += v3;
        qa0 += v0*v0; qa1 += v1*v1; qa2 += v2*v2; qa3 += v3*v3;
    }
    atomicAdd(&ss[ch0  ], sa0); atomicAdd(&sq[ch0  ], qa0);
    atomicAdd(&ss[ch0+1], sa1); atomicAdd(&sq[ch0+1], qa1);
    atomicAdd(&ss[ch0+2], sa2); atomicAdd(&sq[ch0+2], qa2);
    atomicAdd(&ss[ch0+3], sa3); atomicAdd(&sq[ch0+3], qa3);
    __syncthreads();
    atomicAdd(&st1[tid], ss[tid]);
    atomicAdd(&st1[CC + tid], sq[tid]);
}
__global__ __launch_bounds__(256) void k_num(
        const void* x, const bf16* __restrict__ conv, const void* skw,
        const int* __restrict__ ia, const int2* __restrict__ meta,
        const int* __restrict__ off, const int* __restrict__ list,
        const float* __restrict__ flag,
        bf16* __restrict__ xdf, float* __restrict__ st1){
    if (flag[0] != 0.0f) num_body<bf16>(x, conv, skw, ia, meta, off, list, xdf, st1);
    else                 num_body<float>(x, conv, skw, ia, meta, off, list, xdf, st1);
}

// K6: finalize BN1 only (bias2 moved into k_wt as atomics).
template<typename T>
__device__ void bn1_body(const float* __restrict__ st1, const void* g1, const void* b1,
                         float* __restrict__ ab1){
    const int tid = threadIdx.x;           // 0..255
    const float mean = st1[tid]/(float)RR;
    const float var  = st1[CC + tid]/(float)RR - mean*mean;
    const float a  = ld<T>(g1, tid) * rsqrtf(var + 1e-5f);
    ab1[tid] = a;
    ab1[CC + tid] = ld<T>(b1, tid) - mean*a;
}
__global__ __launch_bounds__(256) void k_bn1(
        const float* __restrict__ st1, const void* g1, const void* b1,
        const float* __restrict__ flag, float* __restrict__ ab1){
    if (flag[0] != 0.0f) bn1_body<bf16>(st1, g1, b1, ab1);
    else                 bn1_body<float>(st1, g1, b1, ab1);
}

// K6b: wTf in MFMA-B fragment layout (bf16) + bias2[o] += bb[c]*w[o,c] atomics.
template<typename T>
__device__ void wt_body(const void* cw, const float* __restrict__ ab1,
                        bf16* __restrict__ wTf, float* __restrict__ bias2){
    const int c = blockIdx.x, o = threadIdx.x;
    const float w = ld<T>(cw, (long long)o*CC + c);
    wTf[(((long long)(o >> 4)*32 + (c >> 3))*16 + (o & 15))*8 + (c & 7)] =
        __float2bfloat16(w * ab1[c]);
    atomicAdd(&bias2[o], w * ab1[CC + c]);
}
__global__ __launch_bounds__(512) void k_wt(
        const void* cw, const float* __restrict__ ab1,
        const float* __restrict__ flag, bf16* __restrict__ wTf,
        float* __restrict__ bias2){
    if (flag[0] != 0.0f) wt_body<bf16>(cw, ab1, wTf, bias2);
    else                 wt_body<float>(cw, ab1, wTf, bias2);
}

// K7: MFMA GEMM. Block = 4 waves; wave = 16 rows x 128 cols.
//     2-D grid (384, 4): mb = blockIdx.x (384 NOT pow2 — do not mask!), nb = blockIdx.y.
__global__ __launch_bounds__(256) void k_gemm(
        const bf16* __restrict__ xdf, const bf16* __restrict__ wTf,
        const float* __restrict__ bias2, const float* __restrict__ flag,
        void* __restrict__ y, float* __restrict__ st2){
    __shared__ float ss[128], sq[128];
    const int tid = threadIdx.x;
    if (tid < 128){ ss[tid] = 0.f; sq[tid] = 0.f; }
    __syncthreads();
    const int wave = tid >> 6;
    const int lane = tid & 63;
    const int l16 = lane & 15;
    const int lq  = lane >> 4;
    const int mb = blockIdx.x;              // 0..383
    const int nb = blockIdx.y;              // 0..3
    const int mt = mb*4 + wave;             // m-tile (16 rows)
    const int n0t = nb*8;                   // first n-tile
    const short* ap = (const short*)xdf + ((long long)mt*32 + lq)*128 + (long long)l16*8;
    const short* bp = (const short*)wTf + ((long long)n0t*32 + lq)*128 + (long long)l16*8;
    f32x4 acc[8];
    #pragma unroll
    for (int nt = 0; nt < 8; ++nt) acc[nt] = (f32x4){0.f,0.f,0.f,0.f};
    #pragma unroll
    for (int kg0 = 0; kg0 < 8; ++kg0){
        const bf16x8 af = *((const bf16x8*)(ap + kg0*512));
        #pragma unroll
        for (int nt = 0; nt < 8; ++nt){
            const bf16x8 bfr = *((const bf16x8*)(bp + (long long)nt*4096 + kg0*512));
            acc[nt] = __builtin_amdgcn_mfma_f32_16x16x32_bf16(af, bfr, acc[nt], 0, 0, 0);
        }
    }
    const int row0 = mt*16 + lq*4;
    const bool isbf = (flag[0] != 0.0f);
    #pragma unroll
    for (int nt = 0; nt < 8; ++nt){
        const int col = nb*128 + nt*16 + l16;
        const float bz = bias2[col];
        float s = 0.f, q = 0.f;
        float v[4];
        #pragma unroll
        for (int r = 0; r < 4; ++r){
            v[r] = acc[nt][r] + bz;
            s += v[r]; q += v[r]*v[r];
        }
        if (isbf){
            bf16* yo = (bf16*)y;
            #pragma unroll
            for (int r = 0; r < 4; ++r)
                yo[(long long)(row0 + r)*CCO + col] = __float2bfloat16(v[r]);
        } else {
            float* yo = (float*)y;
            #pragma unroll
            for (int r = 0; r < 4; ++r)
                yo[(long long)(row0 + r)*CCO + col] = v[r];
        }
        s += __shfl_xor(s, 16); s += __shfl_xor(s, 32);
        q += __shfl_xor(q, 16); q += __shfl_xor(q, 32);
        if (lq == 0){
            atomicAdd(&ss[nt*16 + l16], s);
            atomicAdd(&sq[nt*16 + l16], q);
        }
    }
    __syncthreads();
    if (tid < 128){
        atomicAdd(&st2[nb*128 + tid], ss[tid]);
        atomicAdd(&st2[CCO + nb*128 + tid], sq[tid]);
    }
}

// K8: finalize BN2 scale/shift.
template<typename T>
__device__ void bn2_body(const float* __restrict__ st2, const void* g2, const void* b2,
                         float* __restrict__ ab2){
    const int tid = threadIdx.x;
    const float mean = st2[tid]/(float)RR;
    const float var  = st2[CCO + tid]/(float)RR - mean*mean;
    const float a = ld<T>(g2, tid) * rsqrtf(var + 1e-5f);
    ab2[tid] = a;
    ab2[CCO + tid] = ld<T>(b2, tid) - mean*a;
}
__global__ __launch_bounds__(512) void k_bn2(
        const float* __restrict__ st2, const void* g2, const void* b2,
        const float* __restrict__ flag, float* __restrict__ ab2){
    if (flag[0] != 0.0f) bn2_body<bf16>(st2, g2, b2, ab2);
    else                 bn2_body<float>(st2, g2, b2, ab2);
}

// K9: in-place on d_out: out = relu(y*a2 + b2), 4 elems/thread.
__global__ __launch_bounds__(256) void k_out(
        void* __restrict__ y, const float* __restrict__ ab2,
        const float* __restrict__ flag){
    const long long i0 = ((long long)blockIdx.x*256 + threadIdx.x)*4;
    const int o0 = (int)(i0 & (CCO-1));
    if (flag[0] != 0.0f){
        unsigned short* p = (unsigned short*)y;
        ushort4 u = *(ushort4*)(p + i0);
        float v0 = bfu(u.x)*ab2[o0  ] + ab2[CCO + o0  ];
        float v1 = bfu(u.y)*ab2[o0+1] + ab2[CCO + o0+1];
        float v2 = bfu(u.z)*ab2[o0+2] + ab2[CCO + o0+2];
        float v3 = bfu(u.w)*ab2[o0+3] + ab2[CCO + o0+3];
        u.x = ubf(fmaxf(v0,0.f)); u.y = ubf(fmaxf(v1,0.f));
        u.z = ubf(fmaxf(v2,0.f)); u.w = ubf(fmaxf(v3,0.f));
        *(ushort4*)(p + i0) = u;
    } else {
        float* p = (float*)y;
        float4 v = *(float4*)(p + i0);
        v.x = fmaxf(v.x*ab2[o0  ] + ab2[CCO + o0  ], 0.f);
        v.y = fmaxf(v.y*ab2[o0+1] + ab2[CCO + o0+1], 0.f);
        v.z = fmaxf(v.z*ab2[o0+2] + ab2[CCO + o0+2], 0.f);
        v.w = fmaxf(v.w*ab2[o0+3] + ab2[CCO + o0+3], 0.f);
        *(float4*)(p + i0) = v;
    }
}

extern "C" void kernel_launch(void* const* d_in, const int* in_sizes, int n_in,
                              void* d_out, int out_size, void* d_ws, size_t ws_size,
                              hipStream_t stream){
    (void)in_sizes; (void)n_in; (void)out_size; (void)ws_size;
    const void* x   = d_in[0];
    const void* loc = d_in[1];
    const int*  ia  = (const int*)d_in[2];
    const int*  iat = (const int*)d_in[5];
    const void* wt  = d_in[6];
    const void* dww = d_in[9];
    const void* skw = d_in[10];
    const void* g1  = d_in[11];
    const void* b1  = d_in[12];
    const void* cw  = d_in[13];
    const void* g2  = d_in[14];
    const void* b2  = d_in[15];
    float* ws = (float*)d_ws;
    float* flag = ws + O_FLAG;
    int*  off  = (int*)(ws + O_OFF);
    int*  list = (int*)(ws + O_LIST);
    int*  aux  = (int*)(ws + O_AUX);
    int2* meta = (int2*)(ws + O_META);
    bf16* conv = (bf16*)(ws + O_CONV);
    bf16* xdf  = (bf16*)(ws + O_XD);
    bf16* wTf  = (bf16*)(ws + O_WT);

    // zero ST1(512) + ST2(1024) + AB1(512, harmless) + B2(512) = 2560 words
    hipMemsetAsync(ws + O_ST1, 0, (size_t)2560*4, stream);
    hipMemsetAsync(off, 0, (size_t)SCN*4, stream);

    k_flag<<<dim3(1), dim3(64), 0, stream>>>((const float*)loc, flag);

    k_meta<<<dim3(NTOK/256), dim3(256), 0, stream>>>(loc, iat, wt, flag, meta, off);

    k_scan1<<<dim3(SCB), dim3(1024), 0, stream>>>(off, aux);
    k_scan2<<<dim3(1), dim3(128), 0, stream>>>(aux);
    k_scan3<<<dim3(SCB), dim3(1024), 0, stream>>>(off, aux);

    k_fill<<<dim3(NTOK/256), dim3(256), 0, stream>>>(loc, ia, iat, flag, off, list);

    k_conv<<<dim3(BB*HW2), dim3(192), 0, stream>>>(x, dww, flag, off, list, conv);

    k_num<<<dim3(RR/(4*TGW)), dim3(256), 0, stream>>>(
        x, conv, skw, ia, meta, off, list, flag, xdf, ws + O_ST1);

    k_bn1<<<dim3(1), dim3(256), 0, stream>>>(
        ws + O_ST1, g1, b1, flag, ws + O_AB1);

    k_wt<<<dim3(CC), dim3(512), 0, stream>>>(cw, ws + O_AB1, flag, wTf, ws + O_B2);

    k_gemm<<<dim3(384, 4), dim3(256), 0, stream>>>(
        xdf, wTf, ws + O_B2, flag, d_out, ws + O_ST2);

    k_bn2<<<dim3(1), dim3(512), 0, stream>>>(ws + O_ST2, g2, b2, flag, ws + O_AB2);

    k_out<<<dim3((RR*CCO)/1024, 1), dim3(256), 0, stream>>>(d_out, ws + O_AB2, flag);
}

// Round 4
// 358.106 us; speedup vs baseline: 1.1821x; 1.1310x over previous
//
#include <hip/hip_runtime.h>
#include <hip/hip_bf16.h>

using bf16 = __hip_bfloat16;
typedef __attribute__((ext_vector_type(8))) short bf16x8;
typedef __attribute__((ext_vector_type(4))) float f32x4;

#define BB   8
#define NN   12288
#define NTOK (BB*NN)      // 98304
#define NTK  3072
#define CC   256
#define CCO  512
#define HH   128
#define WWI  96
#define HWIN (HH*WWI)     // 12288
#define H2   64
#define W2   48
#define HW2  (H2*W2)      // 3072
#define RR   (BB*NTK)     // 24576

// ---- workspace layout (float-word offsets)
#define O_CONV  0LL          // conv bf16: 6291456 elems -> 3145728 words
#define O_XD    6291456LL    // xdf bf16 fragment layout: 6291456 elems -> 3145728 words
#define O_AUX   9437184LL    // 128 ints (scan block sums)
#define O_ST2P  9437440LL    // 8192 words: 8 partials x (512 sum | 512 sumsq)
#define O_WT    12582912LL   // wTf bf16 fragment layout: 131072 elems -> 65536 words
#define O_ST1   12713984LL   // 512
#define O_ST2   12714496LL   // 1024 (unused now, kept for layout stability)
#define O_AB1   12715520LL   // 512
#define O_B2    12716032LL   // 512
#define O_AB2   12716544LL   // 1024
#define O_FLAG  12717568LL   // 4
#define O_META  12717572LL   // 196608 (int2 per token {hw2, wv})
#define O_OFF   12914180LL   // 122880 ints: joint [cells(98304) | targets(24576)]
#define O_LIST  13037060LL   // 196608 ints: joint [listA | listB]
// end 13233668

__device__ __forceinline__ float cvt(float v){ return v; }
__device__ __forceinline__ float cvt(bf16 v){ return __bfloat162float(v); }
template<typename T>
__device__ __forceinline__ float ld(const void* p, long long i){
    return cvt(((const T*)p)[i]);
}
__device__ __forceinline__ float bfu(unsigned short u){
    return __uint_as_float((unsigned)u << 16);
}
__device__ __forceinline__ unsigned short ubf(float f){
    bf16 h = __float2bfloat16(f);
    return *(unsigned short*)&h;
}
// load 4 consecutive elements (first index i, i%4==0) as f32x4
template<typename T>
__device__ __forceinline__ f32x4 ld4(const void* p, long long i);
template<>
__device__ __forceinline__ f32x4 ld4<bf16>(const void* p, long long i){
    const ushort4 u = *(const ushort4*)((const unsigned short*)p + i);
    return (f32x4){bfu(u.x), bfu(u.y), bfu(u.z), bfu(u.w)};
}
template<>
__device__ __forceinline__ f32x4 ld4<float>(const void* p, long long i){
    const float4 v = *(const float4*)((const float*)p + i);
    return (f32x4){v.x, v.y, v.z, v.w};
}

// dtype detector: loc_orig ~ U(-1,1); f32 words all in [-1,1], bf16-reinterp huge.
__global__ void k_flag(const float* __restrict__ locf, float* __restrict__ flag){
    if (threadIdx.x == 0){
        int bad = 0;
        for (int i = 0; i < 64; ++i){
            const float v = locf[i];
            if (!(v >= -1.0f && v <= 1.0f)) bad = 1;
        }
        flag[0] = bad ? 1.0f : 0.0f;
    }
}

__device__ __forceinline__ int2 gidx2(float lx, float ly, int h, int w){
    lx = fminf(fmaxf(lx, -1.f), 1.f);
    ly = fminf(fmaxf(ly, -1.f), 1.f);
    int xi = (int)rintf(0.5f*(lx+1.f)*(float)w - 0.5f);
    int yi = (int)rintf(0.5f*(ly+1.f)*(float)h - 0.5f);
    xi = min(max(xi,0), w-1); yi = min(max(yi,0), h-1);
    return make_int2(xi, yi);
}

// K1: meta {hw2, wv} + joint histogram (cells then targets).
template<typename T>
__device__ void meta_body(const void* loc, const int* __restrict__ iat, const void* wt,
                          int2* __restrict__ meta, int* __restrict__ off){
    const int tok = blockIdx.x*256 + threadIdx.x;
    const int b = tok / NN;
    const float lx = ld<T>(loc, 2LL*tok);
    const float ly = ld<T>(loc, 2LL*tok + 1);
    const int2 g1 = gidx2(lx, ly, HH, WWI);
    const int2 g2 = gidx2(lx, ly, H2, W2);
    const float wv = ld<T>(wt, tok);
    int2 m; m.x = g2.x + g2.y*W2; m.y = __float_as_int(wv);
    meta[tok] = m;
    atomicAdd(&off[b*HWIN + g1.x + g1.y*WWI], 1);
    atomicAdd(&off[NTOK + b*NTK + iat[tok]], 1);
}
__global__ __launch_bounds__(256) void k_meta(
        const void* loc, const int* __restrict__ iat, const void* wt,
        const float* __restrict__ flag, int2* __restrict__ meta,
        int* __restrict__ off){
    if (flag[0] != 0.0f) meta_body<bf16>(loc, iat, wt, meta, off);
    else                 meta_body<float>(loc, iat, wt, meta, off);
}

// Scan over joint off[122880]: S1 per-block excl scan + totals, S2 scan totals, S3 add.
#define SCN  (NTOK + RR)     // 122880
#define SCB  120             // 120 blocks x 1024
__global__ __launch_bounds__(1024) void k_scan1(int* __restrict__ off, int* __restrict__ aux){
    __shared__ int sm[1024];
    const int tid = threadIdx.x;
    const int gid = blockIdx.x*1024 + tid;
    const int v = off[gid];
    sm[tid] = v;
    __syncthreads();
    for (int d = 1; d < 1024; d <<= 1){
        const int t = (tid >= d) ? sm[tid-d] : 0;
        __syncthreads();
        sm[tid] += t;
        __syncthreads();
    }
    off[gid] = sm[tid] - v;                    // exclusive within block
    if (tid == 1023) aux[blockIdx.x] = sm[1023];
}
__global__ __launch_bounds__(128) void k_scan2(int* __restrict__ aux){
    __shared__ int sm[128];
    const int tid = threadIdx.x;
    const int v = (tid < SCB) ? aux[tid] : 0;
    sm[tid] = v;
    __syncthreads();
    for (int d = 1; d < 128; d <<= 1){
        const int t = (tid >= d) ? sm[tid-d] : 0;
        __syncthreads();
        sm[tid] += t;
        __syncthreads();
    }
    if (tid < SCB) aux[tid] = sm[tid] - v;     // exclusive
}
__global__ __launch_bounds__(1024) void k_scan3(int* __restrict__ off, const int* __restrict__ aux){
    off[blockIdx.x*1024 + threadIdx.x] += aux[blockIdx.x];
}

// K3: fill joint CSR list. After this off holds inclusive ends.
template<typename T>
__device__ void fill_body(const void* loc, const int* __restrict__ ia,
                          const int* __restrict__ iat,
                          int* __restrict__ off, int* __restrict__ list){
    const int tok = blockIdx.x*256 + threadIdx.x;
    const int b = tok / NN;
    const float lx = ld<T>(loc, 2LL*tok);
    const float ly = ld<T>(loc, 2LL*tok + 1);
    const int2 g1 = gidx2(lx, ly, HH, WWI);
    const int pa = atomicAdd(&off[b*HWIN + g1.x + g1.y*WWI], 1);
    list[pa] = b*NN + ia[tok];
    const int pb = atomicAdd(&off[NTOK + b*NTK + iat[tok]], 1);
    list[pb] = tok;
}
__global__ __launch_bounds__(256) void k_fill(
        const void* loc, const int* __restrict__ ia, const int* __restrict__ iat,
        const float* __restrict__ flag,
        int* __restrict__ off, int* __restrict__ list){
    if (flag[0] != 0.0f) fill_body<bf16>(loc, ia, iat, off, list);
    else                 fill_body<float>(loc, ia, iat, off, list);
}

// K4: gather-conv, wave-per-(cell,row). Block = 192 thr = 3 waves (wave = kh).
// Per wave: one uniform off fetch, lane-parallel list batch, 4-unrolled x-row
// loads, bucket binning by list index. Rows combine via LDS; wave 0 stores.
template<typename T>
__device__ void conv_body(const void* x, const void* dww,
                          const int* __restrict__ off, const int* __restrict__ list,
                          bf16* __restrict__ conv){
    __shared__ f32x4 red[3][64];
    const int tid = threadIdx.x;
    const int kh = tid >> 6;                       // 0..2 (wave = kernel row)
    const int lane = tid & 63;
    const int ch0 = lane*4;
    const int cell = blockIdx.x;                   // 0..24575
    const int b = cell / HW2;
    const int p = cell % HW2;
    const int oh = p / W2, ow = p % W2;
    const int ih = 2*oh - 1 + kh;                  // [-1, 127]; only -1 invalid
    f32x4 part = (f32x4){0.f,0.f,0.f,0.f};
    if (ih >= 0){
        const int gbase = b*HWIN + ih*WWI + 2*ow - 1;   // cell of kw=0
        const int e0 = (gbase >= 0) ? off[gbase] : 0;   // end kw=0 / start kw=1
        const int e1 = off[gbase+1];
        const int e2 = off[gbase+2];
        const int ms = (ow > 0) ? off[gbase-1] : e0;    // merged start
        // 3 taps x 4 channels for this row (independent, issued early)
        f32x4 w0, w1, w2;
        #pragma unroll
        for (int c = 0; c < 4; ++c){
            w0[c] = ld<T>(dww, (long long)(ch0+c)*9 + kh*3 + 0);
            w1[c] = ld<T>(dww, (long long)(ch0+c)*9 + kh*3 + 1);
            w2[c] = ld<T>(dww, (long long)(ch0+c)*9 + kh*3 + 2);
        }
        f32x4 b0 = (f32x4){0.f,0.f,0.f,0.f};
        f32x4 b1 = (f32x4){0.f,0.f,0.f,0.f};
        f32x4 b2 = (f32x4){0.f,0.f,0.f,0.f};
        int idx = ms;
        while (idx < e2){
            const int cnt = min(e2 - idx, 64);
            const int tokv = (lane < cnt) ? list[idx + lane] : 0;
            int j = 0;
            for (; j + 4 <= cnt; j += 4){
                int oxs[4];
                #pragma unroll
                for (int u = 0; u < 4; ++u)
                    oxs[u] = __shfl(tokv, j+u)*CC + ch0;
                f32x4 xv[4];
                #pragma unroll
                for (int u = 0; u < 4; ++u) xv[u] = ld4<T>(x, (long long)oxs[u]);
                #pragma unroll
                for (int u = 0; u < 4; ++u){
                    const int gi = idx + j + u;        // uniform
                    if (gi < e0)      b0 += xv[u];
                    else if (gi < e1) b1 += xv[u];
                    else              b2 += xv[u];
                }
            }
            for (; j < cnt; ++j){
                const f32x4 xv = ld4<T>(x, (long long)(__shfl(tokv, j)*CC + ch0));
                const int gi = idx + j;
                if (gi < e0)      b0 += xv;
                else if (gi < e1) b1 += xv;
                else              b2 += xv;
            }
            idx += cnt;
        }
        const float r0 = 1.0f/((float)(e0 - ms) + 1e-6f);
        const float r1 = 1.0f/((float)(e1 - e0) + 1e-6f);
        const float r2 = 1.0f/((float)(e2 - e1) + 1e-6f);
        #pragma unroll
        for (int c = 0; c < 4; ++c)
            part[c] = w0[c]*b0[c]*r0 + w1[c]*b1[c]*r1 + w2[c]*b2[c]*r2;
    }
    red[kh][lane] = part;
    __syncthreads();
    if (kh == 0){
        const f32x4 t0 = red[0][lane];
        const f32x4 t1 = red[1][lane];
        const f32x4 t2 = red[2][lane];
        ushort4 o;
        o.x = ubf(t0[0]+t1[0]+t2[0]);
        o.y = ubf(t0[1]+t1[1]+t2[1]);
        o.z = ubf(t0[2]+t1[2]+t2[2]);
        o.w = ubf(t0[3]+t1[3]+t2[3]);
        *(ushort4*)((unsigned short*)conv + (long long)cell*CC + ch0) = o;
    }
}
__global__ __launch_bounds__(192) void k_conv(
        const void* x, const void* dww, const float* __restrict__ flag,
        const int* __restrict__ off, const int* __restrict__ list,
        bf16* __restrict__ conv){
    if (flag[0] != 0.0f) conv_body<bf16>(x, dww, off, list, conv);
    else                 conv_body<float>(x, dww, off, list, conv);
}

// K5 (R4): revert to the measured-best R1 gather structure (TGW=4, wave-per-
// target serial, lane-parallel list/meta/ia prefetch + broadcast) and REMOVE
// all BN1-stats work (no LDS, no syncthreads, no atomics). Writes xdf only.
// Stats are computed by k_st1 from xdf afterwards.
#define TGW 4
template<typename T>
__device__ void num_body(const void* x, const bf16* __restrict__ conv,
                         const void* skw, const int* __restrict__ ia,
                         const int2* __restrict__ meta,
                         const int* __restrict__ off, const int* __restrict__ list,
                         bf16* __restrict__ xdf){
    const int tid = threadIdx.x;
    const int wave = tid >> 6;
    const int lane = tid & 63;
    const int ch0 = lane*4;
    const f32x4 sk = ld4<T>(skw, ch0);
    const int W = blockIdx.x*4 + wave;             // global wave id, 0..6143
    for (int t = 0; t < TGW; ++t){
        const int gt = W*TGW + t;                  // target 0..24575
        const int b = gt / NTK;
        const int gj = NTOK + gt;
        const int e  = off[gj];
        const int s  = off[gj-1];
        f32x4 a = (f32x4){0.f,0.f,0.f,0.f};
        float den = 0.f;
        int idx = s;
        while (idx < e){
            const int cnt = min(e - idx, 64);
            int tok = 0, ja = 0; int2 m = make_int2(0, 0);
            if (lane < cnt){
                tok = list[idx + lane];
                m = meta[tok];
                ja = ia[tok];
            }
            for (int j = 0; j < cnt; ++j){
                const float wv = __int_as_float(__shfl(m.y, j));
                const int rx = b*NN  + __shfl(ja, j);
                const int rc = b*HW2 + __shfl(m.x, j);
                const f32x4 xv = ld4<T>(x, (long long)rx*CC + ch0);
                const f32x4 cv = ld4<bf16>(conv, (long long)rc*CC + ch0);
                #pragma unroll
                for (int c = 0; c < 4; ++c)
                    a[c] += wv*(sk[c]*xv[c] + cv[c]);
                den += wv;
            }
            idx += cnt;
        }
        const float rl = 1.0f/(den + 1e-6f);
        ushort4 o;
        o.x = ubf(a[0]*rl); o.y = ubf(a[1]*rl);
        o.z = ubf(a[2]*rl); o.w = ubf(a[3]*rl);
        const long long bi = (long long)(gt >> 4)*4096 + (long long)(ch0 >> 3)*128
                           + (long long)(gt & 15)*8 + (ch0 & 7);
        *(ushort4*)((unsigned short*)xdf + bi) = o;
    }
}
__global__ __launch_bounds__(256) void k_num(
        const void* x, const bf16* __restrict__ conv, const void* skw,
        const int* __restrict__ ia, const int2* __restrict__ meta,
        const int* __restrict__ off, const int* __restrict__ list,
        const float* __restrict__ flag,
        bf16* __restrict__ xdf){
    if (flag[0] != 0.0f) num_body<bf16>(x, conv, skw, ia, meta, off, list, xdf);
    else                 num_body<float>(x, conv, skw, ia, meta, off, list, xdf);
}

// K5b: BN1 stats from xdf (12.6 MB bf16, streaming). Fragment layout octet view:
// octet o = sb*512 + cg*16 + tl holds channels cg*8..cg*8+7 of one target.
// Thread keeps cg fixed -> register accumulation; LDS reduce; 1 atomic/ch/block.
__global__ __launch_bounds__(512) void k_st1(const bf16* __restrict__ xdf,
                                             float* __restrict__ st1){
    __shared__ float ss[CC], sq[CC];
    const int tid = threadIdx.x;
    if (tid < CC){ ss[tid] = 0.f; sq[tid] = 0.f; }
    __syncthreads();
    const int tl = tid & 15;
    const int cg = tid >> 4;          // 0..31, channel group
    const int c0 = cg*8;
    float s[8], q[8];
    #pragma unroll
    for (int k = 0; k < 8; ++k){ s[k] = 0.f; q[k] = 0.f; }
    for (int sb = blockIdx.x; sb < RR/16; sb += gridDim.x){
        const long long o = (long long)sb*512 + cg*16 + tl;
        const bf16x8 v = *((const bf16x8*)xdf + o);
        #pragma unroll
        for (int k = 0; k < 8; ++k){
            const float f = bfu((unsigned short)v[k]);
            s[k] += f; q[k] += f*f;
        }
    }
    #pragma unroll
    for (int k = 0; k < 8; ++k){
        atomicAdd(&ss[c0+k], s[k]);
        atomicAdd(&sq[c0+k], q[k]);
    }
    __syncthreads();
    if (tid < CC){
        atomicAdd(&st1[tid], ss[tid]);
        atomicAdd(&st1[CC + tid], sq[tid]);
    }
}

// K6: finalize BN1 only (bias2 computed in k_wt as atomics).
template<typename T>
__device__ void bn1_body(const float* __restrict__ st1, const void* g1, const void* b1,
                         float* __restrict__ ab1){
    const int tid = threadIdx.x;           // 0..255
    const float mean = st1[tid]/(float)RR;
    const float var  = st1[CC + tid]/(float)RR - mean*mean;
    const float a  = ld<T>(g1, tid) * rsqrtf(var + 1e-5f);
    ab1[tid] = a;
    ab1[CC + tid] = ld<T>(b1, tid) - mean*a;
}
__global__ __launch_bounds__(256) void k_bn1(
        const float* __restrict__ st1, const void* g1, const void* b1,
        const float* __restrict__ flag, float* __restrict__ ab1){
    if (flag[0] != 0.0f) bn1_body<bf16>(st1, g1, b1, ab1);
    else                 bn1_body<float>(st1, g1, b1, ab1);
}

// K6b: wTf in MFMA-B fragment layout (bf16) + bias2[o] += bb[c]*w[o,c] atomics.
template<typename T>
__device__ void wt_body(const void* cw, const float* __restrict__ ab1,
                        bf16* __restrict__ wTf, float* __restrict__ bias2){
    const int c = blockIdx.x, o = threadIdx.x;
    const float w = ld<T>(cw, (long long)o*CC + c);
    wTf[(((long long)(o >> 4)*32 + (c >> 3))*16 + (o & 15))*8 + (c & 7)] =
        __float2bfloat16(w * ab1[c]);
    atomicAdd(&bias2[o], w * ab1[CC + c]);
}
__global__ __launch_bounds__(512) void k_wt(
        const void* cw, const float* __restrict__ ab1,
        const float* __restrict__ flag, bf16* __restrict__ wTf,
        float* __restrict__ bias2){
    if (flag[0] != 0.0f) wt_body<bf16>(cw, ab1, wTf, bias2);
    else                 wt_body<float>(cw, ab1, wTf, bias2);
}

// K7: MFMA GEMM. Block = 4 waves; wave = 16 rows x 128 cols.
//     2-D grid (384, 4). BN2 stats into 8-way partials (contention 384 -> 48).
__global__ __launch_bounds__(256) void k_gemm(
        const bf16* __restrict__ xdf, const bf16* __restrict__ wTf,
        const float* __restrict__ bias2, const float* __restrict__ flag,
        void* __restrict__ y, float* __restrict__ st2p){
    __shared__ float ss[128], sq[128];
    const int tid = threadIdx.x;
    if (tid < 128){ ss[tid] = 0.f; sq[tid] = 0.f; }
    __syncthreads();
    const int wave = tid >> 6;
    const int lane = tid & 63;
    const int l16 = lane & 15;
    const int lq  = lane >> 4;
    const int mb = blockIdx.x;              // 0..383
    const int nb = blockIdx.y;              // 0..3
    const int mt = mb*4 + wave;             // m-tile (16 rows)
    const int n0t = nb*8;                   // first n-tile
    const short* ap = (const short*)xdf + ((long long)mt*32 + lq)*128 + (long long)l16*8;
    const short* bp = (const short*)wTf + ((long long)n0t*32 + lq)*128 + (long long)l16*8;
    f32x4 acc[8];
    #pragma unroll
    for (int nt = 0; nt < 8; ++nt) acc[nt] = (f32x4){0.f,0.f,0.f,0.f};
    #pragma unroll
    for (int kg0 = 0; kg0 < 8; ++kg0){
        const bf16x8 af = *((const bf16x8*)(ap + kg0*512));
        #pragma unroll
        for (int nt = 0; nt < 8; ++nt){
            const bf16x8 bfr = *((const bf16x8*)(bp + (long long)nt*4096 + kg0*512));
            acc[nt] = __builtin_amdgcn_mfma_f32_16x16x32_bf16(af, bfr, acc[nt], 0, 0, 0);
        }
    }
    const int row0 = mt*16 + lq*4;
    const bool isbf = (flag[0] != 0.0f);
    #pragma unroll
    for (int nt = 0; nt < 8; ++nt){
        const int col = nb*128 + nt*16 + l16;
        const float bz = bias2[col];
        float s = 0.f, q = 0.f;
        float v[4];
        #pragma unroll
        for (int r = 0; r < 4; ++r){
            v[r] = acc[nt][r] + bz;
            s += v[r]; q += v[r]*v[r];
        }
        if (isbf){
            bf16* yo = (bf16*)y;
            #pragma unroll
            for (int r = 0; r < 4; ++r)
                yo[(long long)(row0 + r)*CCO + col] = __float2bfloat16(v[r]);
        } else {
            float* yo = (float*)y;
            #pragma unroll
            for (int r = 0; r < 4; ++r)
                yo[(long long)(row0 + r)*CCO + col] = v[r];
        }
        s += __shfl_xor(s, 16); s += __shfl_xor(s, 32);
        q += __shfl_xor(q, 16); q += __shfl_xor(q, 32);
        if (lq == 0){
            atomicAdd(&ss[nt*16 + l16], s);
            atomicAdd(&sq[nt*16 + l16], q);
        }
    }
    __syncthreads();
    if (tid < 128){
        const int slot = (mb & 7)*1024;
        atomicAdd(&st2p[slot + nb*128 + tid], ss[tid]);
        atomicAdd(&st2p[slot + 512 + nb*128 + tid], sq[tid]);
    }
}

// K8: finalize BN2 scale/shift from 8 partials.
template<typename T>
__device__ void bn2_body(const float* __restrict__ st2p, const void* g2, const void* b2,
                         float* __restrict__ ab2){
    const int tid = threadIdx.x;           // 0..511
    float s = 0.f, q = 0.f;
    #pragma unroll
    for (int p = 0; p < 8; ++p){
        s += st2p[p*1024 + tid];
        q += st2p[p*1024 + 512 + tid];
    }
    const float mean = s/(float)RR;
    const float var  = q/(float)RR - mean*mean;
    const float a = ld<T>(g2, tid) * rsqrtf(var + 1e-5f);
    ab2[tid] = a;
    ab2[CCO + tid] = ld<T>(b2, tid) - mean*a;
}
__global__ __launch_bounds__(512) void k_bn2(
        const float* __restrict__ st2p, const void* g2, const void* b2,
        const float* __restrict__ flag, float* __restrict__ ab2){
    if (flag[0] != 0.0f) bn2_body<bf16>(st2p, g2, b2, ab2);
    else                 bn2_body<float>(st2p, g2, b2, ab2);
}

// K9: in-place on d_out: out = relu(y*a2 + b2), 4 elems/thread.
__global__ __launch_bounds__(256) void k_out(
        void* __restrict__ y, const float* __restrict__ ab2,
        const float* __restrict__ flag){
    const long long i0 = ((long long)blockIdx.x*256 + threadIdx.x)*4;
    const int o0 = (int)(i0 & (CCO-1));
    if (flag[0] != 0.0f){
        unsigned short* p = (unsigned short*)y;
        ushort4 u = *(ushort4*)(p + i0);
        float v0 = bfu(u.x)*ab2[o0  ] + ab2[CCO + o0  ];
        float v1 = bfu(u.y)*ab2[o0+1] + ab2[CCO + o0+1];
        float v2 = bfu(u.z)*ab2[o0+2] + ab2[CCO + o0+2];
        float v3 = bfu(u.w)*ab2[o0+3] + ab2[CCO + o0+3];
        u.x = ubf(fmaxf(v0,0.f)); u.y = ubf(fmaxf(v1,0.f));
        u.z = ubf(fmaxf(v2,0.f)); u.w = ubf(fmaxf(v3,0.f));
        *(ushort4*)(p + i0) = u;
    } else {
        float* p = (float*)y;
        float4 v = *(float4*)(p + i0);
        v.x = fmaxf(v.x*ab2[o0  ] + ab2[CCO + o0  ], 0.f);
        v.y = fmaxf(v.y*ab2[o0+1] + ab2[CCO + o0+1], 0.f);
        v.z = fmaxf(v.z*ab2[o0+2] + ab2[CCO + o0+2], 0.f);
        v.w = fmaxf(v.w*ab2[o0+3] + ab2[CCO + o0+3], 0.f);
        *(float4*)(p + i0) = v;
    }
}

extern "C" void kernel_launch(void* const* d_in, const int* in_sizes, int n_in,
                              void* d_out, int out_size, void* d_ws, size_t ws_size,
                              hipStream_t stream){
    (void)in_sizes; (void)n_in; (void)out_size; (void)ws_size;
    const void* x   = d_in[0];
    const void* loc = d_in[1];
    const int*  ia  = (const int*)d_in[2];
    const int*  iat = (const int*)d_in[5];
    const void* wt  = d_in[6];
    const void* dww = d_in[9];
    const void* skw = d_in[10];
    const void* g1  = d_in[11];
    const void* b1  = d_in[12];
    const void* cw  = d_in[13];
    const void* g2  = d_in[14];
    const void* b2  = d_in[15];
    float* ws = (float*)d_ws;
    float* flag = ws + O_FLAG;
    int*  off  = (int*)(ws + O_OFF);
    int*  list = (int*)(ws + O_LIST);
    int*  aux  = (int*)(ws + O_AUX);
    int2* meta = (int2*)(ws + O_META);
    bf16* conv = (bf16*)(ws + O_CONV);
    bf16* xdf  = (bf16*)(ws + O_XD);
    bf16* wTf  = (bf16*)(ws + O_WT);

    // zero ST1(512)+ST2(1024)+AB1(512)+B2(512) = 2560 words, st2p(8192), off
    hipMemsetAsync(ws + O_ST1, 0, (size_t)2560*4, stream);
    hipMemsetAsync(ws + O_ST2P, 0, (size_t)8192*4, stream);
    hipMemsetAsync(off, 0, (size_t)SCN*4, stream);

    k_flag<<<dim3(1), dim3(64), 0, stream>>>((const float*)loc, flag);

    k_meta<<<dim3(NTOK/256), dim3(256), 0, stream>>>(loc, iat, wt, flag, meta, off);

    k_scan1<<<dim3(SCB), dim3(1024), 0, stream>>>(off, aux);
    k_scan2<<<dim3(1), dim3(128), 0, stream>>>(aux);
    k_scan3<<<dim3(SCB), dim3(1024), 0, stream>>>(off, aux);

    k_fill<<<dim3(NTOK/256), dim3(256), 0, stream>>>(loc, ia, iat, flag, off, list);

    k_conv<<<dim3(BB*HW2), dim3(192), 0, stream>>>(x, dww, flag, off, list, conv);

    k_num<<<dim3(RR/(4*TGW)), dim3(256), 0, stream>>>(
        x, conv, skw, ia, meta, off, list, flag, xdf);

    k_st1<<<dim3(192), dim3(512), 0, stream>>>(xdf, ws + O_ST1);

    k_bn1<<<dim3(1), dim3(256), 0, stream>>>(
        ws + O_ST1, g1, b1, flag, ws + O_AB1);

    k_wt<<<dim3(CC), dim3(512), 0, stream>>>(cw, ws + O_AB1, flag, wTf, ws + O_B2);

    k_gemm<<<dim3(384, 4), dim3(256), 0, stream>>>(
        xdf, wTf, ws + O_B2, flag, d_out, ws + O_ST2P);

    k_bn2<<<dim3(1), dim3(512), 0, stream>>>(ws + O_ST2P, g2, b2, flag, ws + O_AB2);

    k_out<<<dim3((RR*CCO)/1024, 1), dim3(256), 0, stream>>>(d_out, ws + O_AB2, flag);
}